// Round 8
// baseline (285.736 us; speedup 1.0000x reference)
//
#include <hip/hip_runtime.h>
#include <hip/hip_bf16.h>
#include <math.h>

#define HD   2048
#define DD   128
#define TT   4096
#define BB   4
#define MT   (BB*TT)     // 16384 tokens
#define LSEG 64
#define SSEG 64
#define NCOL 256
#define SCALE_D 0.088388347648318447f  // 1/sqrt(128)

typedef _Float16 half8 __attribute__((ext_vector_type(8)));
typedef _Float16 half4v __attribute__((ext_vector_type(4)));
typedef float    f32x4 __attribute__((ext_vector_type(4)));

__device__ __forceinline__ float sigmf(float x){ return 1.f/(1.f+__expf(-x)); }

__device__ __forceinline__ void glds16(const void* g, void* l) {
  __builtin_amdgcn_global_load_lds(
      (const __attribute__((address_space(1))) unsigned int*)g,
      (__attribute__((address_space(3))) unsigned int*)l, 16, 0, 0);
}

// ---------------------------------------------------------------------------
// K_pre: pack B' = g (.) [sp_w | W_q] as fp16, n-major [256][2048], LINEAR
// storage (R5-proven). Per-col sums s_n, cb_n; we2 = g*w_eta;
// scal = {s_eta, cb_eta, 0, 0}
// ---------------------------------------------------------------------------
__global__ void k_pre(const float* __restrict__ ln_g, const float* __restrict__ ln_b,
                      const float* __restrict__ sp_w, const float* __restrict__ sp_b,
                      const float* __restrict__ W_qkv, const float* __restrict__ W_eta_w,
                      const float* __restrict__ W_eta_b,
                      _Float16* __restrict__ Bp, float* __restrict__ s_vec,
                      float* __restrict__ cb_vec, float* __restrict__ we2,
                      float* __restrict__ scal)
{
  __shared__ float red1[256], red2[256];
  int n = blockIdx.x, t = threadIdx.x;
  float sp = 0.f, cp = 0.f;
  if (n < NCOL) {
    for (int h = t; h < HD; h += 256) {
      float w = (n < DD) ? sp_w[(size_t)h*DD + n] : W_qkv[(size_t)h*384 + 256 + (n-DD)];
      float g = ln_g[h], b = ln_b[h];
      Bp[(size_t)n*HD + h] = (_Float16)(g*w);
      sp += g*w; cp += b*w;
    }
  } else {
    for (int h = t; h < HD; h += 256) {
      float w = W_eta_w[h];
      float g = ln_g[h], b = ln_b[h];
      we2[h] = g*w;
      sp += g*w; cp += b*w;
    }
  }
  red1[t] = sp; red2[t] = cp;
  __syncthreads();
  for (int o = 128; o > 0; o >>= 1) {
    if (t < o) { red1[t] += red1[t+o]; red2[t] += red2[t+o]; }
    __syncthreads();
  }
  if (t == 0) {
    if (n < NCOL) {
      s_vec[n]  = red1[0];
      cb_vec[n] = red2[0] + ((n < DD) ? sp_b[n] : 0.f);
    } else {
      scal[0] = red1[0];
      scal[1] = red2[0] + W_eta_b[0];
      scal[2] = 0.f; scal[3] = 0.f;
    }
  }
}

// ---------------------------------------------------------------------------
// K01 R13: fused LN-stats + GEMM + segment ops. Grid 512, 256 thr, 4 waves.
// A (H) staged as f32 LDS tiles via global_load_lds, TRIPLE-buffered with a
// counted vmcnt(4) so A(t+2) stays in flight across 2 barriers (T3/T4).
// B (Bp, L2-hot) double-buffered glds, drained each barrier (covered).
// A source-side XOR quad swizzle (dest linear): LDS quad (row,dq) holds
// source quad dq^(row&15) -> 0-conflict frag reads, 2-way stats reads.
// Per-wave per-iter VMEM order (sched_barrier-pinned):
//   [we(t) x4 reg loads][glds B(t+1) x4][glds A(t+2) x4][compute][vmcnt(4)]
// vmcnt(4) keeps only A(t+2); drains B(t+1), A(t+1), anything older.
// LDS: A 3x16K + B 2x16K = 80KB exact (2 blocks/CU); small arrays alias
// into the post-loop-dead sA2 region; sHm aliases pool after stats barrier.
// ---------------------------------------------------------------------------
__launch_bounds__(256, 2)
__global__ void k01(const float* __restrict__ H, const _Float16* __restrict__ Bp,
                    const float* __restrict__ s_vec, const float* __restrict__ cb_vec,
                    const float* __restrict__ we2, const float* __restrict__ scal,
                    const float* __restrict__ sum_q, const float* __restrict__ Mmat,
                    const float* __restrict__ temp,
                    float* __restrict__ Q_r, float* __restrict__ Zeta,
                    float* __restrict__ A_seg, float* __restrict__ eta_seg)
{
  __shared__ __align__(16) char pool[81920];
  // k-loop: sA f32 tiles @0/16K/32K, sB fp16 tiles @48K/64K
  char* const sA0b = pool;
  char* const sA1b = pool + 16384;
  char* const sA2b = pool + 32768;
  char* const sB0b = pool + 49152;
  char* const sB1b = pool + 65536;
  // post-loop aliases (all >= 32768, inside sA2 which is dead after kt=29;
  // sHm spans 0..33792 but is only written after the stats barrier)
  float* sHm    = (float*)pool;              // 64*132*4 = 33792 B
  float* smu    = (float*)(pool + 33792);    // 64 f
  float* srs    = (float*)(pool + 34048);    // 64 f
  float* seta   = (float*)(pool + 34304);    // 64 f
  float* sq_s   = (float*)(pool + 34560);    // 128 f
  float* w64_s  = (float*)(pool + 35072);    // 64 f
  float* Zs     = (float*)(pool + 35328);    // 128 f
  float* red_s  = (float*)(pool + 35840);    // 4 f
  float* eta_shp= (float*)(pool + 35856);    // 1 f

  int tid = threadIdx.x;
  int seg = blockIdx.x >> 1, ntile = blockIdx.x & 1;
  int b   = seg >> 6;
  int m0  = seg * 64;
  int n0  = ntile * 128;
  int w = tid >> 6, lane = tid & 63, fcol = lane & 15, kq = lane >> 4;

  // A glds params: 4 calls/wave, call j=w*4+c stages rows j*4..j*4+3.
  // lane l: row = j*4 + (l>>4), source quad = (l&15) ^ (row&15) (involution).
  const float* asrc[4]; int aldst[4];
#pragma unroll
  for (int c = 0; c < 4; ++c) {
    int j = w*4 + c;
    int row = j*4 + (lane >> 4);
    int q = (lane & 15) ^ (row & 15);
    asrc[c]  = H + (size_t)(m0 + row)*HD + q*4;
    aldst[c] = j*1024 + lane*16;
  }
  // B glds params (R12-proven: linear dest, XOR'd source chunk)
  int bn[4], bsl[4];
#pragma unroll
  for (int i = 0; i < 4; ++i) {
    int idx = i*256 + tid;
    bn[i]  = idx >> 3;
    bsl[i] = (idx & 7) ^ (bn[i] & 7);
  }
  // stats strip: 4 threads/row, 16 floats each
  int sR = tid >> 2, sS = tid & 3, sRx = (tid >> 2) & 15;
  const float* wep = we2 + sS*16;

  f32x4 acc[4][2];
#pragma unroll
  for (int i = 0; i < 4; ++i)
#pragma unroll
    for (int j = 0; j < 2; ++j) acc[i][j] = (f32x4){0.f,0.f,0.f,0.f};
  float s1 = 0.f, s2 = 0.f, se = 0.f;
  float4 pw0, pw1, pw2, pw3;

#define SB0() __builtin_amdgcn_sched_barrier(0)

#define LOAD_WE(k0v)                                                          \
  { const float* wp = wep + (k0v);                                            \
    pw0 = *(const float4*)(wp + 0); pw1 = *(const float4*)(wp + 4);           \
    pw2 = *(const float4*)(wp + 8); pw3 = *(const float4*)(wp + 12); }

#define GLDS_B(k0v, dst)                                                      \
  _Pragma("unroll")                                                           \
  for (int i = 0; i < 4; ++i)                                                 \
    glds16(Bp + (size_t)(n0 + bn[i])*HD + (k0v) + bsl[i]*8,                   \
           (dst) + (i*256 + tid)*16);

#define GLDS_A(k0v, dst)                                                      \
  _Pragma("unroll")                                                           \
  for (int c = 0; c < 4; ++c)                                                 \
    glds16(asrc[c] + (k0v), (dst) + aldst[c]);

#define COMPUTE_T(sAc, sBc)                                                   \
  { const float* Af = (const float*)(sAc);                                    \
    const _Float16* Bf = (const _Float16*)(sBc);                              \
    __builtin_amdgcn_s_setprio(1);                                            \
    _Pragma("unroll")                                                         \
    for (int ks = 0; ks < 2; ++ks) {                                          \
      half8 af[4], bf[2];                                                     \
      _Pragma("unroll")                                                       \
      for (int rt = 0; rt < 4; ++rt) {                                        \
        int r = rt*16 + fcol; int rx = r & 15; int q0 = ks*8 + kq*2;          \
        f32x4 x0 = *(const f32x4*)&Af[r*64 + ((q0    ) ^ rx)*4];              \
        f32x4 x1 = *(const f32x4*)&Af[r*64 + ((q0 + 1) ^ rx)*4];              \
        half8 h;                                                              \
        h[0]=(_Float16)x0[0]; h[1]=(_Float16)x0[1];                           \
        h[2]=(_Float16)x0[2]; h[3]=(_Float16)x0[3];                           \
        h[4]=(_Float16)x1[0]; h[5]=(_Float16)x1[1];                           \
        h[6]=(_Float16)x1[2]; h[7]=(_Float16)x1[3];                           \
        af[rt] = h;                                                           \
      }                                                                       \
      _Pragma("unroll")                                                       \
      for (int ct = 0; ct < 2; ++ct) {                                        \
        int n = w*32 + ct*16 + fcol;                                          \
        int ch = (ks*4 + kq) ^ (n & 7);                                       \
        bf[ct] = *(const half8*)&Bf[n*64 + ch*8];                             \
      }                                                                       \
      _Pragma("unroll")                                                       \
      for (int rt = 0; rt < 4; ++rt)                                          \
        _Pragma("unroll")                                                     \
        for (int ct = 0; ct < 2; ++ct)                                        \
          acc[rt][ct] = __builtin_amdgcn_mfma_f32_16x16x32_f16(af[rt], bf[ct], acc[rt][ct], 0,0,0); \
    }                                                                         \
    __builtin_amdgcn_s_setprio(0);                                            \
    float v[16];                                                              \
    _Pragma("unroll")                                                         \
    for (int i = 0; i < 4; ++i)                                               \
      *(f32x4*)&v[i*4] = *(const f32x4*)&Af[sR*64 + ((sS*4 + i) ^ sRx)*4];    \
    float uu[16] = {pw0.x,pw0.y,pw0.z,pw0.w, pw1.x,pw1.y,pw1.z,pw1.w,         \
                    pw2.x,pw2.y,pw2.z,pw2.w, pw3.x,pw3.y,pw3.z,pw3.w};        \
    _Pragma("unroll")                                                         \
    for (int j = 0; j < 16; ++j) { s1 += v[j]; s2 += v[j]*v[j]; se += v[j]*uu[j]; } \
  }

  // ---- prologue: we(0); A(0)->sA0; B(0)->sB0; A(1)->sA1; keep A(1) ----
  LOAD_WE(0);
  SB0();
  GLDS_A(0, sA0b);
  SB0();
  GLDS_B(0, sB0b);
  SB0();
  GLDS_A(64, sA1b);
  SB0();
  asm volatile("s_waitcnt vmcnt(4)" ::: "memory");
  __builtin_amdgcn_s_barrier();
  SB0();

  char* sAc = sA0b; char* sAn1 = sA1b; char* sAn2 = sA2b;
  char* sBc = sB0b; char* sBn = sB1b;

  for (int kt = 0; kt < 30; ++kt) {
    int k0 = kt*64;
    LOAD_WE(k0);              // we(t) regs (oldest VMEM this iter)
    SB0();
    GLDS_B(k0 + 64, sBn);     // B(t+1), drained at this iter's end
    SB0();
    GLDS_A(k0 + 128, sAn2);   // A(t+2), stays in flight across barrier
    SB0();
    COMPUTE_T(sAc, sBc);      // compiler use-wait for we drains only older
    SB0();
    asm volatile("s_waitcnt vmcnt(4)" ::: "memory");   // keep A(t+2) only
    asm volatile("s_waitcnt lgkmcnt(0)" ::: "memory");
    __builtin_amdgcn_s_barrier();
    SB0();
    { char* t0p = sAc; sAc = sAn1; sAn1 = sAn2; sAn2 = t0p; }
    { char* t1p = sBc; sBc = sBn; sBn = t1p; }
  }
  // kt = 30: no A issue; drain everything at the barrier
  LOAD_WE(1920);
  SB0();
  GLDS_B(1984, sBn);
  SB0();
  COMPUTE_T(sAc, sBc);
  SB0();
  asm volatile("s_waitcnt vmcnt(0)" ::: "memory");
  asm volatile("s_waitcnt lgkmcnt(0)" ::: "memory");
  __builtin_amdgcn_s_barrier();
  SB0();
  { char* t0p = sAc; sAc = sAn1; sAn1 = sAn2; sAn2 = t0p; }
  { char* t1p = sBc; sBc = sBn; sBn = t1p; }
  // kt = 31: pure compute
  LOAD_WE(1984);
  COMPUTE_T(sAc, sBc);

  // row stats: reduce across the 4 strip-threads of each row (same wave)
  float scal0 = scal[0], scal1 = scal[1];
  if (tid < 128) sq_s[tid] = sum_q[tid];   // in sA2 region: safe pre-barrier
  s1 += __shfl_xor(s1, 1); s1 += __shfl_xor(s1, 2);
  s2 += __shfl_xor(s2, 1); s2 += __shfl_xor(s2, 2);
  se += __shfl_xor(se, 1); se += __shfl_xor(se, 2);
  if ((tid & 3) == 0) {
    int row = tid >> 2;
    float mu   = s1 * (1.f/HD);
    float var  = s2 * (1.f/HD) - mu*mu;
    float rstd = rsqrtf(var + 1e-5f);
    smu[row] = mu; srs[row] = rstd;
    seta[row] = rstd*(se - mu*scal0) + scal1;
  }
  __syncthreads();   // stats visible; ALL waves' loop reads done -> pool reusable

  // epilogue: LN affine -> sHm (local cols 0..127)
#pragma unroll
  for (int ct = 0; ct < 2; ++ct) {
    int nl = w*32 + ct*16 + fcol;
    float sn = s_vec[n0 + nl], cbn = cb_vec[n0 + nl];
#pragma unroll
    for (int rt = 0; rt < 4; ++rt)
#pragma unroll
      for (int r = 0; r < 4; ++r) {
        int m = rt*16 + kq*4 + r;
        sHm[m*132 + nl] = srs[m]*(acc[rt][ct][r] - smu[m]*sn) + cbn;
      }
  }
  __syncthreads();   // sHm ready

  if (ntile == 1) {
    // coalesced Q_r writes
#pragma unroll
    for (int j = 0; j < 8; ++j) {
      int idx = j*256 + tid;
      int row = idx >> 5, c4 = (idx & 31)*4;
      *(float4*)&Q_r[(size_t)(m0 + row)*DD + c4] = *(float4*)&sHm[row*132 + c4];
    }
    return;
  }

  // ---- ntile0: segment ops on H_mem in LDS ----
  if (w == 0) {
    float sc = 0.f;
    const float4* hrow = (const float4*)&sHm[lane*132];
#pragma unroll
    for (int d4 = 0; d4 < 32; ++d4) {
      float4 hv = hrow[d4];
      float4 qv = *(const float4*)&sq_s[d4*4];
      sc += hv.x*qv.x + hv.y*qv.y + hv.z*qv.z + hv.w*qv.w;
    }
    sc *= SCALE_D;
    float mx = sc;
    for (int o = 32; o > 0; o >>= 1) mx = fmaxf(mx, __shfl_xor(mx, o));
    float e = __expf(sc - mx);
    float sm = e;
    for (int o = 32; o > 0; o >>= 1) sm += __shfl_xor(sm, o);
    w64_s[lane] = e / sm;
  } else if (w == 1) {
    float ev = seta[lane];
    for (int o = 32; o > 0; o >>= 1) ev = fmaxf(ev, __shfl_xor(ev, o));
    if (lane == 0) { float es = sigmf(ev); eta_shp[0] = es; eta_seg[seg] = es; }
  }
  __syncthreads();   // w64_s, eta_shp ready

  // Z[d] + Zeta
  if (tid < 128) {
    float z = 0.f;
    for (int l = 0; l < 64; ++l) z += w64_s[l]*sHm[l*132 + tid];
    Zs[tid] = z;
    Zeta[(size_t)seg*DD + tid] = z * eta_shp[0];
  }
  __syncthreads();   // Zs ready

  // write-attn scores over K=128 + softmax (flat barriers, R5-proven form)
  float sc2 = 0.f;
  if (tid < 128) {
    const float4* mrow = (const float4*)(Mmat + ((size_t)b*DD + tid)*DD);
#pragma unroll
    for (int d4 = 0; d4 < 32; ++d4) {
      float4 mv = mrow[d4];
      sc2 += mv.x*Zs[d4*4] + mv.y*Zs[d4*4+1] + mv.z*Zs[d4*4+2] + mv.w*Zs[d4*4+3];
    }
    sc2 *= SCALE_D * __expf(temp[0]);
    float mx = sc2;
    for (int o = 32; o > 0; o >>= 1) mx = fmaxf(mx, __shfl_xor(mx, o));
    if (lane == 0) red_s[w] = mx;
  }
  __syncthreads();
  float ev2 = 0.f;
  if (tid < 128) {
    float mx = fmaxf(red_s[0], red_s[1]);
    ev2 = __expf(sc2 - mx);
    float sm = ev2;
    for (int o = 32; o > 0; o >>= 1) sm += __shfl_xor(sm, o);
    if (lane == 0) red_s[2 + w] = sm;
  }
  __syncthreads();
  if (tid < 128) {
    float smt = red_s[2] + red_s[3];
    A_seg[(size_t)seg*DD + tid] = ev2 / smt;
  }
}

// ---------------------------------------------------------------------------
// K2b: DeltaM (k-chunk of 32 per block), M_new, row rnorms, norm_sq atomic.
// ---------------------------------------------------------------------------
__global__ void k2b(const float* __restrict__ A_seg, const float* __restrict__ Zeta,
                    const float* __restrict__ eta_seg, const float* __restrict__ Mmat,
                    const float* __restrict__ eta_ch,
                    float* __restrict__ M_new, float* __restrict__ rns_arr,
                    float* __restrict__ scal)
{
  __shared__ float As[64][33];
  __shared__ __align__(16) float Zsl[64*128];
  __shared__ float rowp[32][8];
  __shared__ float eta_av;
  __shared__ float redb[4];
  int tid = threadIdx.x;
  int b = blockIdx.x >> 2, kq = blockIdx.x & 3;
  for (int i = tid; i < 64*32; i += 256) {
    int s = i >> 5, j = i & 31;
    As[s][j] = A_seg[((size_t)b*SSEG + s)*DD + kq*32 + j];
  }
  const float4* z4 = (const float4*)(Zeta + (size_t)b*SSEG*DD);
  float4* zs4 = (float4*)Zsl;
  for (int i = tid; i < 64*32; i += 256) zs4[i] = z4[i];
  if (tid < 64) {
    float ev = eta_seg[(size_t)b*SSEG + tid];
    for (int o=32;o>0;o>>=1) ev += __shfl_xor(ev, o);
    if (tid == 0) eta_av = ev * (1.f/SSEG);
  }
  __syncthreads();
  int kl = tid & 31, dg = tid >> 5;
  int k = kq*32 + kl, d0 = dg*16;
  float dm[16];
#pragma unroll
  for (int j=0;j<16;j++) dm[j]=0.f;
  for (int s = 0; s < 64; ++s) {
    float a = As[s][kl];
    const float* zr = &Zsl[s*128 + d0];
#pragma unroll
    for (int j=0;j<16;j++) dm[j] += a * zr[j];
  }
  float nsq = 0.f;
#pragma unroll
  for (int j=0;j<16;j++) nsq += dm[j]*dm[j];
  float eav = eta_av;
  float mn[16];
  float ss = 0.f;
#pragma unroll
  for (int j=0;j<16;j++) {
    int d = d0 + j;
    float gate = eav * sigmf(eta_ch[d]);
    float v = (1.f - gate)*Mmat[((size_t)b*DD + k)*DD + d] + dm[j]*(1.f/SSEG);
    mn[j] = v; ss += v*v;
  }
#pragma unroll
  for (int j=0;j<16;j+=4) {
    float4 v4; v4.x=mn[j]; v4.y=mn[j+1]; v4.z=mn[j+2]; v4.w=mn[j+3];
    *(float4*)&M_new[((size_t)b*DD + k)*DD + d0 + j] = v4;
  }
  rowp[kl][dg] = ss;
  for (int o=1;o<64;o<<=1) nsq += __shfl_xor(nsq, o);
  if ((tid&63)==0) redb[tid>>6] = nsq;
  __syncthreads();
  if (tid == 0) atomicAdd(&scal[2], redb[0]+redb[1]+redb[2]+redb[3]);
  if (tid < 32) {
    float t2 = 0.f;
#pragma unroll
    for (int g=0; g<8; ++g) t2 += rowp[tid][g];
    float nrm = sqrtf(t2);
    rns_arr[(size_t)b*DD + kq*32 + tid] = 1.f / fmaxf(nrm, 1e-12f);
  }
}

// ---------------------------------------------------------------------------
// K2d: diversity loss partials.
// ---------------------------------------------------------------------------
__global__ void k2d(const float* __restrict__ M_new, const float* __restrict__ rns_arr,
                    float* __restrict__ scal)
{
  __shared__ float kr[4][128];
  __shared__ float redb[4];
  int tid = threadIdx.x;
  int b = blockIdx.x >> 5, kq = blockIdx.x & 31;
  for (int i = tid; i < 4*128; i += 256) {
    int ki = i >> 7, d = i & 127;
    kr[ki][d] = M_new[((size_t)b*DD + kq*4 + ki)*DD + d];
  }
  __syncthreads();
  int j = tid & 127, kh = tid >> 7;
  const float* mj = &M_new[((size_t)b*DD + j)*DD];
  float rj = rns_arr[(size_t)b*DD + j];
  float dv = 0.f;
#pragma unroll
  for (int ki2 = 0; ki2 < 2; ++ki2) {
    int kil = kh*2 + ki2;
    int kk = kq*4 + kil;
    float dot = 0.f;
    for (int d = 0; d < 128; d += 4) {
      float4 a = *(const float4*)(mj + d);
      dot += a.x*kr[kil][d] + a.y*kr[kil][d+1] + a.z*kr[kil][d+2] + a.w*kr[kil][d+3];
    }
    if (kk != j) {
      float sv = dot * rj * rns_arr[(size_t)b*DD + kk];
      dv += sv*sv;
    }
  }
  for (int o=1;o<64;o<<=1) dv += __shfl_xor(dv, o);
  if ((tid&63)==0) redb[tid>>6] = dv;
  __syncthreads();
  if (tid==0) atomicAdd(&scal[3], redb[0]+redb[1]+redb[2]+redb[3]);
}

// ---------------------------------------------------------------------------
// K3: read attention via MFMA fp16 (fp32 softmax/accum). R12-proven:
// 512 blocks x 128 threads (32-token tiles), LDS 77KB -> 2 blocks/CU.
// ---------------------------------------------------------------------------
__launch_bounds__(128, 1)
__global__ void k3(const float* __restrict__ Q_r, const float* __restrict__ M_new,
                   const float* __restrict__ scal, float* __restrict__ out)
{
  __shared__ __align__(16) _Float16 Mq[128*132];  // [key][d]   (QK B-frags)
  __shared__ __align__(16) _Float16 Mt[128*136];  // [d][key]   (PV B-frags)
  __shared__ __align__(16) _Float16 Ps[32*132];   // [token][key] (PV A-frags)
  int tid = threadIdx.x;
  int b = blockIdx.x >> 7, tile = blockIdx.x & 127;
  int t0 = tile*32;
  if (blockIdx.x == 0 && tid == 0) {
    float loss = 0.01f*(scal[2]*(1.f/SSEG)) + 0.1f*(scal[3]*(1.f/(BB*DD*DD)));
    out[(size_t)MT*DD] = loss;
  }
  const float4* m4 = (const float4*)(M_new + (size_t)b*DD*DD);
#pragma unroll
  for (int it = 0; it < 8; ++it) {
    int sb = it*128 + tid;
    int rb = sb & 31, cb = sb >> 5;
    int r0 = rb*4, c0 = cb*4;
    float a[4][4];
#pragma unroll
    for (int j = 0; j < 4; ++j) {
      float4 v = m4[(size_t)(r0+j)*32 + cb];
      a[j][0]=v.x; a[j][1]=v.y; a[j][2]=v.z; a[j][3]=v.w;
    }
#pragma unroll
    for (int j = 0; j < 4; ++j) {
      half4v h; h.x=(_Float16)a[j][0]; h.y=(_Float16)a[j][1];
                h.z=(_Float16)a[j][2]; h.w=(_Float16)a[j][3];
      *(half4v*)&Mq[(r0+j)*132 + c0] = h;
    }
#pragma unroll
    for (int j2 = 0; j2 < 4; ++j2) {
      half4v h; h.x=(_Float16)a[0][j2]; h.y=(_Float16)a[1][j2];
                h.z=(_Float16)a[2][j2]; h.w=(_Float16)a[3][j2];
      *(half4v*)&Mt[(c0+j2)*136 + r0] = h;
    }
  }
  int w = tid >> 6, lane = tid & 63;
  int fcol = lane & 15, kq = lane >> 4;
  int tokA = t0 + w*16 + fcol;
  size_t qbase = ((size_t)b*TT + tokA)*DD;
  half8 af[4];
#pragma unroll
  for (int ks = 0; ks < 4; ++ks) {
    float4 q0 = *(const float4*)&Q_r[qbase + ks*32 + kq*8];
    float4 q1 = *(const float4*)&Q_r[qbase + ks*32 + kq*8 + 4];
    half8 h;
    h[0]=(_Float16)q0.x; h[1]=(_Float16)q0.y; h[2]=(_Float16)q0.z; h[3]=(_Float16)q0.w;
    h[4]=(_Float16)q1.x; h[5]=(_Float16)q1.y; h[6]=(_Float16)q1.z; h[7]=(_Float16)q1.w;
    af[ks] = h;
  }
  __syncthreads();
  f32x4 sacc[8];
#pragma unroll
  for (int nt = 0; nt < 8; ++nt) sacc[nt] = (f32x4){0.f,0.f,0.f,0.f};
#pragma unroll
  for (int nt = 0; nt < 8; ++nt)
#pragma unroll
    for (int ks = 0; ks < 4; ++ks) {
      half8 bf = *(half8*)&Mq[(nt*16 + fcol)*132 + ks*32 + kq*8];
      sacc[nt] = __builtin_amdgcn_mfma_f32_16x16x32_f16(af[ks], bf, sacc[nt], 0,0,0);
    }
#pragma unroll
  for (int nt = 0; nt < 8; ++nt)
#pragma unroll
    for (int r = 0; r < 4; ++r) sacc[nt][r] *= 2.f;
  float mx[4], sm[4];
#pragma unroll
  for (int r = 0; r < 4; ++r) {
    float m = sacc[0][r];
#pragma unroll
    for (int nt = 1; nt < 8; ++nt) m = fmaxf(m, sacc[nt][r]);
#pragma unroll
    for (int o = 1; o < 16; o <<= 1) m = fmaxf(m, __shfl_xor(m, o));
    mx[r] = m;
  }
#pragma unroll
  for (int r = 0; r < 4; ++r) sm[r] = 0.f;
#pragma unroll
  for (int nt = 0; nt < 8; ++nt)
#pragma unroll
    for (int r = 0; r < 4; ++r) {
      float e = __expf(sacc[nt][r] - mx[r]);
      sacc[nt][r] = e; sm[r] += e;
    }
#pragma unroll
  for (int r = 0; r < 4; ++r) {
    float s = sm[r];
#pragma unroll
    for (int o = 1; o < 16; o <<= 1) s += __shfl_xor(s, o);
    sm[r] = 1.f / s;
  }
#pragma unroll
  for (int nt = 0; nt < 8; ++nt)
#pragma unroll
    for (int r = 0; r < 4; ++r) {
      int tk = w*16 + kq*4 + r;
      Ps[tk*132 + nt*16 + fcol] = (_Float16)(sacc[nt][r]*sm[r]);
    }
  __syncthreads();
  half8 pf[4];
#pragma unroll
  for (int ks = 0; ks < 4; ++ks)
    pf[ks] = *(half8*)&Ps[(w*16 + fcol)*132 + ks*32 + kq*8];
  f32x4 cacc[8];
#pragma unroll
  for (int nt = 0; nt < 8; ++nt) cacc[nt] = (f32x4){0.f,0.f,0.f,0.f};
#pragma unroll
  for (int nt = 0; nt < 8; ++nt)
#pragma unroll
    for (int ks = 0; ks < 4; ++ks) {
      half8 bf = *(half8*)&Mt[(nt*16 + fcol)*136 + ks*32 + kq*8];
      cacc[nt] = __builtin_amdgcn_mfma_f32_16x16x32_f16(pf[ks], bf, cacc[nt], 0,0,0);
    }
#pragma unroll
  for (int nt = 0; nt < 8; ++nt)
#pragma unroll
    for (int r = 0; r < 4; ++r) {
      int tk = t0 + w*16 + kq*4 + r;
      out[((size_t)b*TT + tk)*DD + nt*16 + fcol] = cacc[nt][r];
    }
}

// ---------------------------------------------------------------------------
extern "C" void kernel_launch(void* const* d_in, const int* in_sizes, int n_in,
                              void* d_out, int out_size, void* d_ws, size_t ws_size,
                              hipStream_t stream)
{
  (void)in_sizes; (void)n_in; (void)out_size; (void)ws_size;
  const float* H       = (const float*)d_in[0];
  const float* Mmat    = (const float*)d_in[1];
  const float* ln_g    = (const float*)d_in[2];
  const float* ln_b    = (const float*)d_in[3];
  const float* W_eta_w = (const float*)d_in[4];
  const float* W_eta_b = (const float*)d_in[5];
  const float* sum_q   = (const float*)d_in[6];
  const float* sp_w    = (const float*)d_in[7];
  const float* sp_b    = (const float*)d_in[8];
  const float* eta_ch  = (const float*)d_in[9];
  const float* temp    = (const float*)d_in[10];
  const float* W_qkv   = (const float*)d_in[11];
  float* out           = (float*)d_out;

  char* wsb = (char*)d_ws;
  size_t off = 0;
  auto alloc = [&](size_t bytes) -> void* {
    void* p = wsb + off;
    off = (off + bytes + 255) & ~(size_t)255;
    return p;
  };
  _Float16* Bp   = (_Float16*)alloc((size_t)NCOL*HD*2);
  float* s_vec   = (float*)alloc(NCOL*4);
  float* cb_vec  = (float*)alloc(NCOL*4);
  float* we2     = (float*)alloc(HD*4);
  float* scal    = (float*)alloc(4*4);
  float* Q_r     = (float*)alloc((size_t)MT*DD*4);
  float* Zeta    = (float*)alloc((size_t)BB*SSEG*DD*4);
  float* A_seg   = (float*)alloc((size_t)BB*SSEG*DD*4);
  float* eta_seg = (float*)alloc((size_t)BB*SSEG*4);
  float* M_new   = (float*)alloc((size_t)BB*DD*DD*4);
  float* rns_arr = (float*)alloc((size_t)BB*DD*4);

  hipLaunchKernelGGL(k_pre, dim3(NCOL+1), dim3(256), 0, stream,
                     ln_g, ln_b, sp_w, sp_b, W_qkv, W_eta_w, W_eta_b,
                     Bp, s_vec, cb_vec, we2, scal);
  hipLaunchKernelGGL(k01, dim3((MT/64)*2), dim3(256), 0, stream,
                     H, Bp, s_vec, cb_vec, we2, scal, sum_q, Mmat, temp,
                     Q_r, Zeta, A_seg, eta_seg);
  hipLaunchKernelGGL(k2b, dim3(16), dim3(256), 0, stream,
                     A_seg, Zeta, eta_seg, Mmat, eta_ch, M_new, rns_arr, scal);
  hipLaunchKernelGGL(k2d, dim3(128), dim3(256), 0, stream,
                     M_new, rns_arr, scal);
  hipLaunchKernelGGL(k3, dim3(512), dim3(128), 0, stream,
                     Q_r, M_new, scal, out);
}

// Round 9
// 283.442 us; speedup vs baseline: 1.0081x; 1.0081x over previous
//
#include <hip/hip_runtime.h>
#include <hip/hip_bf16.h>
#include <math.h>

#define HD   2048
#define DD   128
#define TT   4096
#define BB   4
#define MT   (BB*TT)     // 16384 tokens
#define LSEG 64
#define SSEG 64
#define NCOL 256
#define SCALE_D 0.088388347648318447f  // 1/sqrt(128)

typedef _Float16 half8 __attribute__((ext_vector_type(8)));
typedef _Float16 half4v __attribute__((ext_vector_type(4)));
typedef float    f32x4 __attribute__((ext_vector_type(4)));

__device__ __forceinline__ float sigmf(float x){ return 1.f/(1.f+__expf(-x)); }

__device__ __forceinline__ void glds16(const void* g, void* l) {
  __builtin_amdgcn_global_load_lds(
      (const __attribute__((address_space(1))) unsigned int*)g,
      (__attribute__((address_space(3))) unsigned int*)l, 16, 0, 0);
}

// ---------------------------------------------------------------------------
// K_pre: pack B' = g (.) [sp_w | W_q] as fp16, n-major [256][2048], LINEAR
// storage (R5-proven). Per-col sums s_n, cb_n; we2 = g*w_eta;
// scal = {s_eta, cb_eta, 0, 0}
// ---------------------------------------------------------------------------
__global__ void k_pre(const float* __restrict__ ln_g, const float* __restrict__ ln_b,
                      const float* __restrict__ sp_w, const float* __restrict__ sp_b,
                      const float* __restrict__ W_qkv, const float* __restrict__ W_eta_w,
                      const float* __restrict__ W_eta_b,
                      _Float16* __restrict__ Bp, float* __restrict__ s_vec,
                      float* __restrict__ cb_vec, float* __restrict__ we2,
                      float* __restrict__ scal)
{
  __shared__ float red1[256], red2[256];
  int n = blockIdx.x, t = threadIdx.x;
  float sp = 0.f, cp = 0.f;
  if (n < NCOL) {
    for (int h = t; h < HD; h += 256) {
      float w = (n < DD) ? sp_w[(size_t)h*DD + n] : W_qkv[(size_t)h*384 + 256 + (n-DD)];
      float g = ln_g[h], b = ln_b[h];
      Bp[(size_t)n*HD + h] = (_Float16)(g*w);
      sp += g*w; cp += b*w;
    }
  } else {
    for (int h = t; h < HD; h += 256) {
      float w = W_eta_w[h];
      float g = ln_g[h], b = ln_b[h];
      we2[h] = g*w;
      sp += g*w; cp += b*w;
    }
  }
  red1[t] = sp; red2[t] = cp;
  __syncthreads();
  for (int o = 128; o > 0; o >>= 1) {
    if (t < o) { red1[t] += red1[t+o]; red2[t] += red2[t+o]; }
    __syncthreads();
  }
  if (t == 0) {
    if (n < NCOL) {
      s_vec[n]  = red1[0];
      cb_vec[n] = red2[0] + ((n < DD) ? sp_b[n] : 0.f);
    } else {
      scal[0] = red1[0];
      scal[1] = red2[0] + W_eta_b[0];
      scal[2] = 0.f; scal[3] = 0.f;
    }
  }
}

// ---------------------------------------------------------------------------
// K01 R14: R13's triple-buffered glds-A pipeline, with the one defect fixed:
// the per-iter we2 register loads are now fetched ONE ITERATION AHEAD into a
// ping-ponged register pair (pwA/pwB, loop unrolled x2 for static names).
// Compute(t) uses we(t) retired at the PREVIOUS barrier's vmcnt(4) (older
// than A(t+2)), so compute has NO VMEM use-wait and A(t+2) genuinely stays
// in flight for ~2 iterations (R13's compiler use-wait vmcnt(8) was
// force-draining A(t+2) one iter early due to in-order retirement).
// ---------------------------------------------------------------------------
__launch_bounds__(256, 2)
__global__ void k01(const float* __restrict__ H, const _Float16* __restrict__ Bp,
                    const float* __restrict__ s_vec, const float* __restrict__ cb_vec,
                    const float* __restrict__ we2, const float* __restrict__ scal,
                    const float* __restrict__ sum_q, const float* __restrict__ Mmat,
                    const float* __restrict__ temp,
                    float* __restrict__ Q_r, float* __restrict__ Zeta,
                    float* __restrict__ A_seg, float* __restrict__ eta_seg)
{
  __shared__ __align__(16) char pool[81920];
  char* const sA0b = pool;
  char* const sA1b = pool + 16384;
  char* const sA2b = pool + 32768;
  char* const sB0b = pool + 49152;
  char* const sB1b = pool + 65536;
  float* sHm    = (float*)pool;              // 64*132*4 = 33792 B
  float* smu    = (float*)(pool + 33792);
  float* srs    = (float*)(pool + 34048);
  float* seta   = (float*)(pool + 34304);
  float* sq_s   = (float*)(pool + 34560);
  float* w64_s  = (float*)(pool + 35072);
  float* Zs     = (float*)(pool + 35328);
  float* red_s  = (float*)(pool + 35840);
  float* eta_shp= (float*)(pool + 35856);

  int tid = threadIdx.x;
  int seg = blockIdx.x >> 1, ntile = blockIdx.x & 1;
  int b   = seg >> 6;
  int m0  = seg * 64;
  int n0  = ntile * 128;
  int w = tid >> 6, lane = tid & 63, fcol = lane & 15, kq = lane >> 4;

  const float* asrc[4]; int aldst[4];
#pragma unroll
  for (int c = 0; c < 4; ++c) {
    int j = w*4 + c;
    int row = j*4 + (lane >> 4);
    int q = (lane & 15) ^ (row & 15);
    asrc[c]  = H + (size_t)(m0 + row)*HD + q*4;
    aldst[c] = j*1024 + lane*16;
  }
  int bn[4], bsl[4];
#pragma unroll
  for (int i = 0; i < 4; ++i) {
    int idx = i*256 + tid;
    bn[i]  = idx >> 3;
    bsl[i] = (idx & 7) ^ (bn[i] & 7);
  }
  int sR = tid >> 2, sS = tid & 3, sRx = (tid >> 2) & 15;
  const float* wep = we2 + sS*16;

  f32x4 acc[4][2];
#pragma unroll
  for (int i = 0; i < 4; ++i)
#pragma unroll
    for (int j = 0; j < 2; ++j) acc[i][j] = (f32x4){0.f,0.f,0.f,0.f};
  float s1 = 0.f, s2 = 0.f, se = 0.f;
  float4 pwA0, pwA1, pwA2, pwA3;   // we(t) for even t
  float4 pwB0, pwB1, pwB2, pwB3;   // we(t) for odd t

#define SB0() __builtin_amdgcn_sched_barrier(0)

#define LOAD_WE_A(k0v)                                                        \
  { const float* wp = wep + (k0v);                                            \
    pwA0 = *(const float4*)(wp + 0); pwA1 = *(const float4*)(wp + 4);         \
    pwA2 = *(const float4*)(wp + 8); pwA3 = *(const float4*)(wp + 12); }

#define LOAD_WE_B(k0v)                                                        \
  { const float* wp = wep + (k0v);                                            \
    pwB0 = *(const float4*)(wp + 0); pwB1 = *(const float4*)(wp + 4);         \
    pwB2 = *(const float4*)(wp + 8); pwB3 = *(const float4*)(wp + 12); }

#define GLDS_B(k0v, dst)                                                      \
  _Pragma("unroll")                                                           \
  for (int i = 0; i < 4; ++i)                                                 \
    glds16(Bp + (size_t)(n0 + bn[i])*HD + (k0v) + bsl[i]*8,                   \
           (dst) + (i*256 + tid)*16);

#define GLDS_A(k0v, dst)                                                      \
  _Pragma("unroll")                                                           \
  for (int c = 0; c < 4; ++c)                                                 \
    glds16(asrc[c] + (k0v), (dst) + aldst[c]);

#define COMPUTE_T(sAc, sBc, qw0, qw1, qw2, qw3)                               \
  { const float* Af = (const float*)(sAc);                                    \
    const _Float16* Bf = (const _Float16*)(sBc);                              \
    __builtin_amdgcn_s_setprio(1);                                            \
    _Pragma("unroll")                                                         \
    for (int ks = 0; ks < 2; ++ks) {                                          \
      half8 af[4], bf[2];                                                     \
      _Pragma("unroll")                                                       \
      for (int rt = 0; rt < 4; ++rt) {                                        \
        int r = rt*16 + fcol; int rx = r & 15; int q0 = ks*8 + kq*2;          \
        f32x4 x0 = *(const f32x4*)&Af[r*64 + ((q0    ) ^ rx)*4];              \
        f32x4 x1 = *(const f32x4*)&Af[r*64 + ((q0 + 1) ^ rx)*4];              \
        half8 h;                                                              \
        h[0]=(_Float16)x0[0]; h[1]=(_Float16)x0[1];                           \
        h[2]=(_Float16)x0[2]; h[3]=(_Float16)x0[3];                           \
        h[4]=(_Float16)x1[0]; h[5]=(_Float16)x1[1];                           \
        h[6]=(_Float16)x1[2]; h[7]=(_Float16)x1[3];                           \
        af[rt] = h;                                                           \
      }                                                                       \
      _Pragma("unroll")                                                       \
      for (int ct = 0; ct < 2; ++ct) {                                        \
        int n = w*32 + ct*16 + fcol;                                          \
        int ch = (ks*4 + kq) ^ (n & 7);                                       \
        bf[ct] = *(const half8*)&Bf[n*64 + ch*8];                             \
      }                                                                       \
      _Pragma("unroll")                                                       \
      for (int rt = 0; rt < 4; ++rt)                                          \
        _Pragma("unroll")                                                     \
        for (int ct = 0; ct < 2; ++ct)                                        \
          acc[rt][ct] = __builtin_amdgcn_mfma_f32_16x16x32_f16(af[rt], bf[ct], acc[rt][ct], 0,0,0); \
    }                                                                         \
    __builtin_amdgcn_s_setprio(0);                                            \
    float v[16];                                                              \
    _Pragma("unroll")                                                         \
    for (int i = 0; i < 4; ++i)                                               \
      *(f32x4*)&v[i*4] = *(const f32x4*)&Af[sR*64 + ((sS*4 + i) ^ sRx)*4];    \
    float uu[16] = {qw0.x,qw0.y,qw0.z,qw0.w, qw1.x,qw1.y,qw1.z,qw1.w,         \
                    qw2.x,qw2.y,qw2.z,qw2.w, qw3.x,qw3.y,qw3.z,qw3.w};        \
    _Pragma("unroll")                                                         \
    for (int j = 0; j < 16; ++j) { s1 += v[j]; s2 += v[j]*v[j]; se += v[j]*uu[j]; } \
  }

#define END_ITER_KEEP_A2()                                                    \
  asm volatile("s_waitcnt vmcnt(4)" ::: "memory");                            \
  asm volatile("s_waitcnt lgkmcnt(0)" ::: "memory");                          \
  __builtin_amdgcn_s_barrier();                                               \
  SB0();                                                                      \
  { char* t0p = sAc; sAc = sAn1; sAn1 = sAn2; sAn2 = t0p; }                   \
  { char* t1p = sBc; sBc = sBn; sBn = t1p; }

  // ---- prologue: we(0)->pwA; A(0); B(0); A(1); keep A(1) in flight ----
  LOAD_WE_A(0);
  SB0();
  GLDS_A(0, sA0b);
  SB0();
  GLDS_B(0, sB0b);
  SB0();
  GLDS_A(64, sA1b);
  SB0();
  asm volatile("s_waitcnt vmcnt(4)" ::: "memory");
  __builtin_amdgcn_s_barrier();
  SB0();

  char* sAc = sA0b; char* sAn1 = sA1b; char* sAn2 = sA2b;
  char* sBc = sB0b; char* sBn = sB1b;

  for (int kt = 0; kt < 30; kt += 2) {
    // ---- even iter t=kt: compute uses pwA=we(t); load we(t+1)->pwB ----
    {
      int k0 = kt*64;
      LOAD_WE_B(k0 + 64);
      SB0();
      GLDS_B(k0 + 64, sBn);
      SB0();
      GLDS_A(k0 + 128, sAn2);
      SB0();
      COMPUTE_T(sAc, sBc, pwA0, pwA1, pwA2, pwA3);
      SB0();
      END_ITER_KEEP_A2();
    }
    // ---- odd iter t=kt+1: compute uses pwB=we(t); load we(t+1)->pwA ----
    {
      int k0 = (kt+1)*64;
      LOAD_WE_A(k0 + 64);
      SB0();
      GLDS_B(k0 + 64, sBn);
      SB0();
      GLDS_A(k0 + 128, sAn2);
      SB0();
      COMPUTE_T(sAc, sBc, pwB0, pwB1, pwB2, pwB3);
      SB0();
      END_ITER_KEEP_A2();
    }
  }
  // kt = 30 (even): compute uses pwA=we(30) (loaded at kt=29); load we(31)->pwB
  LOAD_WE_B(1984);
  SB0();
  GLDS_B(1984, sBn);
  SB0();
  COMPUTE_T(sAc, sBc, pwA0, pwA1, pwA2, pwA3);
  SB0();
  asm volatile("s_waitcnt vmcnt(0)" ::: "memory");
  asm volatile("s_waitcnt lgkmcnt(0)" ::: "memory");
  __builtin_amdgcn_s_barrier();
  SB0();
  { char* t0p = sAc; sAc = sAn1; sAn1 = sAn2; sAn2 = t0p; }
  { char* t1p = sBc; sBc = sBn; sBn = t1p; }
  // kt = 31 (odd): pure compute, uses pwB=we(31)
  COMPUTE_T(sAc, sBc, pwB0, pwB1, pwB2, pwB3);

  // row stats: reduce across the 4 strip-threads of each row (same wave)
  float scal0 = scal[0], scal1 = scal[1];
  if (tid < 128) sq_s[tid] = sum_q[tid];   // in sAn1 region at this point: safe
  s1 += __shfl_xor(s1, 1); s1 += __shfl_xor(s1, 2);
  s2 += __shfl_xor(s2, 1); s2 += __shfl_xor(s2, 2);
  se += __shfl_xor(se, 1); se += __shfl_xor(se, 2);
  if ((tid & 3) == 0) {
    int row = tid >> 2;
    float mu   = s1 * (1.f/HD);
    float var  = s2 * (1.f/HD) - mu*mu;
    float rstd = rsqrtf(var + 1e-5f);
    smu[row] = mu; srs[row] = rstd;
    seta[row] = rstd*(se - mu*scal0) + scal1;
  }
  __syncthreads();   // stats visible; ALL waves' loop reads done -> pool reusable

  // epilogue: LN affine -> sHm (local cols 0..127)
#pragma unroll
  for (int ct = 0; ct < 2; ++ct) {
    int nl = w*32 + ct*16 + fcol;
    float sn = s_vec[n0 + nl], cbn = cb_vec[n0 + nl];
#pragma unroll
    for (int rt = 0; rt < 4; ++rt)
#pragma unroll
      for (int r = 0; r < 4; ++r) {
        int m = rt*16 + kq*4 + r;
        sHm[m*132 + nl] = srs[m]*(acc[rt][ct][r] - smu[m]*sn) + cbn;
      }
  }
  __syncthreads();   // sHm ready

  if (ntile == 1) {
    // coalesced Q_r writes
#pragma unroll
    for (int j = 0; j < 8; ++j) {
      int idx = j*256 + tid;
      int row = idx >> 5, c4 = (idx & 31)*4;
      *(float4*)&Q_r[(size_t)(m0 + row)*DD + c4] = *(float4*)&sHm[row*132 + c4];
    }
    return;
  }

  // ---- ntile0: segment ops on H_mem in LDS ----
  if (w == 0) {
    float sc = 0.f;
    const float4* hrow = (const float4*)&sHm[lane*132];
#pragma unroll
    for (int d4 = 0; d4 < 32; ++d4) {
      float4 hv = hrow[d4];
      float4 qv = *(const float4*)&sq_s[d4*4];
      sc += hv.x*qv.x + hv.y*qv.y + hv.z*qv.z + hv.w*qv.w;
    }
    sc *= SCALE_D;
    float mx = sc;
    for (int o = 32; o > 0; o >>= 1) mx = fmaxf(mx, __shfl_xor(mx, o));
    float e = __expf(sc - mx);
    float sm = e;
    for (int o = 32; o > 0; o >>= 1) sm += __shfl_xor(sm, o);
    w64_s[lane] = e / sm;
  } else if (w == 1) {
    float ev = seta[lane];
    for (int o = 32; o > 0; o >>= 1) ev = fmaxf(ev, __shfl_xor(ev, o));
    if (lane == 0) { float es = sigmf(ev); eta_shp[0] = es; eta_seg[seg] = es; }
  }
  __syncthreads();   // w64_s, eta_shp ready

  // Z[d] + Zeta
  if (tid < 128) {
    float z = 0.f;
    for (int l = 0; l < 64; ++l) z += w64_s[l]*sHm[l*132 + tid];
    Zs[tid] = z;
    Zeta[(size_t)seg*DD + tid] = z * eta_shp[0];
  }
  __syncthreads();   // Zs ready

  // write-attn scores over K=128 + softmax (flat barriers, R5-proven form)
  float sc2 = 0.f;
  if (tid < 128) {
    const float4* mrow = (const float4*)(Mmat + ((size_t)b*DD + tid)*DD);
#pragma unroll
    for (int d4 = 0; d4 < 32; ++d4) {
      float4 mv = mrow[d4];
      sc2 += mv.x*Zs[d4*4] + mv.y*Zs[d4*4+1] + mv.z*Zs[d4*4+2] + mv.w*Zs[d4*4+3];
    }
    sc2 *= SCALE_D * __expf(temp[0]);
    float mx = sc2;
    for (int o = 32; o > 0; o >>= 1) mx = fmaxf(mx, __shfl_xor(mx, o));
    if (lane == 0) red_s[w] = mx;
  }
  __syncthreads();
  float ev2 = 0.f;
  if (tid < 128) {
    float mx = fmaxf(red_s[0], red_s[1]);
    ev2 = __expf(sc2 - mx);
    float sm = ev2;
    for (int o = 32; o > 0; o >>= 1) sm += __shfl_xor(sm, o);
    if (lane == 0) red_s[2 + w] = sm;
  }
  __syncthreads();
  if (tid < 128) {
    float smt = red_s[2] + red_s[3];
    A_seg[(size_t)seg*DD + tid] = ev2 / smt;
  }
}

// ---------------------------------------------------------------------------
// K2b: DeltaM (k-chunk of 32 per block), M_new, row rnorms, norm_sq atomic.
// ---------------------------------------------------------------------------
__global__ void k2b(const float* __restrict__ A_seg, const float* __restrict__ Zeta,
                    const float* __restrict__ eta_seg, const float* __restrict__ Mmat,
                    const float* __restrict__ eta_ch,
                    float* __restrict__ M_new, float* __restrict__ rns_arr,
                    float* __restrict__ scal)
{
  __shared__ float As[64][33];
  __shared__ __align__(16) float Zsl[64*128];
  __shared__ float rowp[32][8];
  __shared__ float eta_av;
  __shared__ float redb[4];
  int tid = threadIdx.x;
  int b = blockIdx.x >> 2, kq = blockIdx.x & 3;
  for (int i = tid; i < 64*32; i += 256) {
    int s = i >> 5, j = i & 31;
    As[s][j] = A_seg[((size_t)b*SSEG + s)*DD + kq*32 + j];
  }
  const float4* z4 = (const float4*)(Zeta + (size_t)b*SSEG*DD);
  float4* zs4 = (float4*)Zsl;
  for (int i = tid; i < 64*32; i += 256) zs4[i] = z4[i];
  if (tid < 64) {
    float ev = eta_seg[(size_t)b*SSEG + tid];
    for (int o=32;o>0;o>>=1) ev += __shfl_xor(ev, o);
    if (tid == 0) eta_av = ev * (1.f/SSEG);
  }
  __syncthreads();
  int kl = tid & 31, dg = tid >> 5;
  int k = kq*32 + kl, d0 = dg*16;
  float dm[16];
#pragma unroll
  for (int j=0;j<16;j++) dm[j]=0.f;
  for (int s = 0; s < 64; ++s) {
    float a = As[s][kl];
    const float* zr = &Zsl[s*128 + d0];
#pragma unroll
    for (int j=0;j<16;j++) dm[j] += a * zr[j];
  }
  float nsq = 0.f;
#pragma unroll
  for (int j=0;j<16;j++) nsq += dm[j]*dm[j];
  float eav = eta_av;
  float mn[16];
  float ss = 0.f;
#pragma unroll
  for (int j=0;j<16;j++) {
    int d = d0 + j;
    float gate = eav * sigmf(eta_ch[d]);
    float v = (1.f - gate)*Mmat[((size_t)b*DD + k)*DD + d] + dm[j]*(1.f/SSEG);
    mn[j] = v; ss += v*v;
  }
#pragma unroll
  for (int j=0;j<16;j+=4) {
    float4 v4; v4.x=mn[j]; v4.y=mn[j+1]; v4.z=mn[j+2]; v4.w=mn[j+3];
    *(float4*)&M_new[((size_t)b*DD + k)*DD + d0 + j] = v4;
  }
  rowp[kl][dg] = ss;
  for (int o=1;o<64;o<<=1) nsq += __shfl_xor(nsq, o);
  if ((tid&63)==0) redb[tid>>6] = nsq;
  __syncthreads();
  if (tid == 0) atomicAdd(&scal[2], redb[0]+redb[1]+redb[2]+redb[3]);
  if (tid < 32) {
    float t2 = 0.f;
#pragma unroll
    for (int g=0; g<8; ++g) t2 += rowp[tid][g];
    float nrm = sqrtf(t2);
    rns_arr[(size_t)b*DD + kq*32 + tid] = 1.f / fmaxf(nrm, 1e-12f);
  }
}

// ---------------------------------------------------------------------------
// K2d: diversity loss partials.
// ---------------------------------------------------------------------------
__global__ void k2d(const float* __restrict__ M_new, const float* __restrict__ rns_arr,
                    float* __restrict__ scal)
{
  __shared__ float kr[4][128];
  __shared__ float redb[4];
  int tid = threadIdx.x;
  int b = blockIdx.x >> 5, kq = blockIdx.x & 31;
  for (int i = tid; i < 4*128; i += 256) {
    int ki = i >> 7, d = i & 127;
    kr[ki][d] = M_new[((size_t)b*DD + kq*4 + ki)*DD + d];
  }
  __syncthreads();
  int j = tid & 127, kh = tid >> 7;
  const float* mj = &M_new[((size_t)b*DD + j)*DD];
  float rj = rns_arr[(size_t)b*DD + j];
  float dv = 0.f;
#pragma unroll
  for (int ki2 = 0; ki2 < 2; ++ki2) {
    int kil = kh*2 + ki2;
    int kk = kq*4 + kil;
    float dot = 0.f;
    for (int d = 0; d < 128; d += 4) {
      float4 a = *(const float4*)(mj + d);
      dot += a.x*kr[kil][d] + a.y*kr[kil][d+1] + a.z*kr[kil][d+2] + a.w*kr[kil][d+3];
    }
    if (kk != j) {
      float sv = dot * rj * rns_arr[(size_t)b*DD + kk];
      dv += sv*sv;
    }
  }
  for (int o=1;o<64;o<<=1) dv += __shfl_xor(dv, o);
  if ((tid&63)==0) redb[tid>>6] = dv;
  __syncthreads();
  if (tid==0) atomicAdd(&scal[3], redb[0]+redb[1]+redb[2]+redb[3]);
}

// ---------------------------------------------------------------------------
// K3: read attention via MFMA fp16 (fp32 softmax/accum). R12-proven:
// 512 blocks x 128 threads (32-token tiles), LDS 77KB -> 2 blocks/CU.
// ---------------------------------------------------------------------------
__launch_bounds__(128, 1)
__global__ void k3(const float* __restrict__ Q_r, const float* __restrict__ M_new,
                   const float* __restrict__ scal, float* __restrict__ out)
{
  __shared__ __align__(16) _Float16 Mq[128*132];  // [key][d]   (QK B-frags)
  __shared__ __align__(16) _Float16 Mt[128*136];  // [d][key]   (PV B-frags)
  __shared__ __align__(16) _Float16 Ps[32*132];   // [token][key] (PV A-frags)
  int tid = threadIdx.x;
  int b = blockIdx.x >> 7, tile = blockIdx.x & 127;
  int t0 = tile*32;
  if (blockIdx.x == 0 && tid == 0) {
    float loss = 0.01f*(scal[2]*(1.f/SSEG)) + 0.1f*(scal[3]*(1.f/(BB*DD*DD)));
    out[(size_t)MT*DD] = loss;
  }
  const float4* m4 = (const float4*)(M_new + (size_t)b*DD*DD);
#pragma unroll
  for (int it = 0; it < 8; ++it) {
    int sb = it*128 + tid;
    int rb = sb & 31, cb = sb >> 5;
    int r0 = rb*4, c0 = cb*4;
    float a[4][4];
#pragma unroll
    for (int j = 0; j < 4; ++j) {
      float4 v = m4[(size_t)(r0+j)*32 + cb];
      a[j][0]=v.x; a[j][1]=v.y; a[j][2]=v.z; a[j][3]=v.w;
    }
#pragma unroll
    for (int j = 0; j < 4; ++j) {
      half4v h; h.x=(_Float16)a[j][0]; h.y=(_Float16)a[j][1];
                h.z=(_Float16)a[j][2]; h.w=(_Float16)a[j][3];
      *(half4v*)&Mq[(r0+j)*132 + c0] = h;
    }
#pragma unroll
    for (int j2 = 0; j2 < 4; ++j2) {
      half4v h; h.x=(_Float16)a[0][j2]; h.y=(_Float16)a[1][j2];
                h.z=(_Float16)a[2][j2]; h.w=(_Float16)a[3][j2];
      *(half4v*)&Mt[(c0+j2)*136 + r0] = h;
    }
  }
  int w = tid >> 6, lane = tid & 63;
  int fcol = lane & 15, kq = lane >> 4;
  int tokA = t0 + w*16 + fcol;
  size_t qbase = ((size_t)b*TT + tokA)*DD;
  half8 af[4];
#pragma unroll
  for (int ks = 0; ks < 4; ++ks) {
    float4 q0 = *(const float4*)&Q_r[qbase + ks*32 + kq*8];
    float4 q1 = *(const float4*)&Q_r[qbase + ks*32 + kq*8 + 4];
    half8 h;
    h[0]=(_Float16)q0.x; h[1]=(_Float16)q0.y; h[2]=(_Float16)q0.z; h[3]=(_Float16)q0.w;
    h[4]=(_Float16)q1.x; h[5]=(_Float16)q1.y; h[6]=(_Float16)q1.z; h[7]=(_Float16)q1.w;
    af[ks] = h;
  }
  __syncthreads();
  f32x4 sacc[8];
#pragma unroll
  for (int nt = 0; nt < 8; ++nt) sacc[nt] = (f32x4){0.f,0.f,0.f,0.f};
#pragma unroll
  for (int nt = 0; nt < 8; ++nt)
#pragma unroll
    for (int ks = 0; ks < 4; ++ks) {
      half8 bf = *(half8*)&Mq[(nt*16 + fcol)*132 + ks*32 + kq*8];
      sacc[nt] = __builtin_amdgcn_mfma_f32_16x16x32_f16(af[ks], bf, sacc[nt], 0,0,0);
    }
#pragma unroll
  for (int nt = 0; nt < 8; ++nt)
#pragma unroll
    for (int r = 0; r < 4; ++r) sacc[nt][r] *= 2.f;
  float mx[4], sm[4];
#pragma unroll
  for (int r = 0; r < 4; ++r) {
    float m = sacc[0][r];
#pragma unroll
    for (int nt = 1; nt < 8; ++nt) m = fmaxf(m, sacc[nt][r]);
#pragma unroll
    for (int o = 1; o < 16; o <<= 1) m = fmaxf(m, __shfl_xor(m, o));
    mx[r] = m;
  }
#pragma unroll
  for (int r = 0; r < 4; ++r) sm[r] = 0.f;
#pragma unroll
  for (int nt = 0; nt < 8; ++nt)
#pragma unroll
    for (int r = 0; r < 4; ++r) {
      float e = __expf(sacc[nt][r] - mx[r]);
      sacc[nt][r] = e; sm[r] += e;
    }
#pragma unroll
  for (int r = 0; r < 4; ++r) {
    float s = sm[r];
#pragma unroll
    for (int o = 1; o < 16; o <<= 1) s += __shfl_xor(s, o);
    sm[r] = 1.f / s;
  }
#pragma unroll
  for (int nt = 0; nt < 8; ++nt)
#pragma unroll
    for (int r = 0; r < 4; ++r) {
      int tk = w*16 + kq*4 + r;
      Ps[tk*132 + nt*16 + fcol] = (_Float16)(sacc[nt][r]*sm[r]);
    }
  __syncthreads();
  half8 pf[4];
#pragma unroll
  for (int ks = 0; ks < 4; ++ks)
    pf[ks] = *(half8*)&Ps[(w*16 + fcol)*132 + ks*32 + kq*8];
  f32x4 cacc[8];
#pragma unroll
  for (int nt = 0; nt < 8; ++nt) cacc[nt] = (f32x4){0.f,0.f,0.f,0.f};
#pragma unroll
  for (int nt = 0; nt < 8; ++nt)
#pragma unroll
    for (int ks = 0; ks < 4; ++ks) {
      half8 bf = *(half8*)&Mt[(nt*16 + fcol)*136 + ks*32 + kq*8];
      cacc[nt] = __builtin_amdgcn_mfma_f32_16x16x32_f16(pf[ks], bf, cacc[nt], 0,0,0);
    }
#pragma unroll
  for (int nt = 0; nt < 8; ++nt)
#pragma unroll
    for (int r = 0; r < 4; ++r) {
      int tk = t0 + w*16 + kq*4 + r;
      out[((size_t)b*TT + tk)*DD + nt*16 + fcol] = cacc[nt][r];
    }
}

// ---------------------------------------------------------------------------
extern "C" void kernel_launch(void* const* d_in, const int* in_sizes, int n_in,
                              void* d_out, int out_size, void* d_ws, size_t ws_size,
                              hipStream_t stream)
{
  (void)in_sizes; (void)n_in; (void)out_size; (void)ws_size;
  const float* H       = (const float*)d_in[0];
  const float* Mmat    = (const float*)d_in[1];
  const float* ln_g    = (const float*)d_in[2];
  const float* ln_b    = (const float*)d_in[3];
  const float* W_eta_w = (const float*)d_in[4];
  const float* W_eta_b = (const float*)d_in[5];
  const float* sum_q   = (const float*)d_in[6];
  const float* sp_w    = (const float*)d_in[7];
  const float* sp_b    = (const float*)d_in[8];
  const float* eta_ch  = (const float*)d_in[9];
  const float* temp    = (const float*)d_in[10];
  const float* W_qkv   = (const float*)d_in[11];
  float* out           = (float*)d_out;

  char* wsb = (char*)d_ws;
  size_t off = 0;
  auto alloc = [&](size_t bytes) -> void* {
    void* p = wsb + off;
    off = (off + bytes + 255) & ~(size_t)255;
    return p;
  };
  _Float16* Bp   = (_Float16*)alloc((size_t)NCOL*HD*2);
  float* s_vec   = (float*)alloc(NCOL*4);
  float* cb_vec  = (float*)alloc(NCOL*4);
  float* we2     = (float*)alloc(HD*4);
  float* scal    = (float*)alloc(4*4);
  float* Q_r     = (float*)alloc((size_t)MT*DD*4);
  float* Zeta    = (float*)alloc((size_t)BB*SSEG*DD*4);
  float* A_seg   = (float*)alloc((size_t)BB*SSEG*DD*4);
  float* eta_seg = (float*)alloc((size_t)BB*SSEG*4);
  float* M_new   = (float*)alloc((size_t)BB*DD*DD*4);
  float* rns_arr = (float*)alloc((size_t)BB*DD*4);

  hipLaunchKernelGGL(k_pre, dim3(NCOL+1), dim3(256), 0, stream,
                     ln_g, ln_b, sp_w, sp_b, W_qkv, W_eta_w, W_eta_b,
                     Bp, s_vec, cb_vec, we2, scal);
  hipLaunchKernelGGL(k01, dim3((MT/64)*2), dim3(256), 0, stream,
                     H, Bp, s_vec, cb_vec, we2, scal, sum_q, Mmat, temp,
                     Q_r, Zeta, A_seg, eta_seg);
  hipLaunchKernelGGL(k2b, dim3(16), dim3(256), 0, stream,
                     A_seg, Zeta, eta_seg, Mmat, eta_ch, M_new, rns_arr, scal);
  hipLaunchKernelGGL(k2d, dim3(128), dim3(256), 0, stream,
                     M_new, rns_arr, scal);
  hipLaunchKernelGGL(k3, dim3(512), dim3(128), 0, stream,
                     Q_r, M_new, scal, out);
}

// Round 10
// 274.415 us; speedup vs baseline: 1.0413x; 1.0329x over previous
//
#include <hip/hip_runtime.h>
#include <hip/hip_bf16.h>
#include <math.h>

#define HD   2048
#define DD   128
#define TT   4096
#define BB   4
#define MT   (BB*TT)     // 16384 tokens
#define LSEG 64
#define SSEG 64
#define NCOL 256
#define SCALE_D 0.088388347648318447f  // 1/sqrt(128)

typedef _Float16 half8 __attribute__((ext_vector_type(8)));
typedef _Float16 half4v __attribute__((ext_vector_type(4)));
typedef float    f32x4 __attribute__((ext_vector_type(4)));

__device__ __forceinline__ float sigmf(float x){ return 1.f/(1.f+__expf(-x)); }

__device__ __forceinline__ void glds16(const void* g, void* l) {
  __builtin_amdgcn_global_load_lds(
      (const __attribute__((address_space(1))) unsigned int*)g,
      (__attribute__((address_space(3))) unsigned int*)l, 16, 0, 0);
}

// ---------------------------------------------------------------------------
// K_pre: pack B' = g (.) [sp_w | W_q] as fp16, n-major [256][2048], LINEAR
// storage (R5-proven). Per-col sums s_n, cb_n; we2 = g*w_eta;
// scal = {s_eta, cb_eta, 0, 0}
// ---------------------------------------------------------------------------
__global__ void k_pre(const float* __restrict__ ln_g, const float* __restrict__ ln_b,
                      const float* __restrict__ sp_w, const float* __restrict__ sp_b,
                      const float* __restrict__ W_qkv, const float* __restrict__ W_eta_w,
                      const float* __restrict__ W_eta_b,
                      _Float16* __restrict__ Bp, float* __restrict__ s_vec,
                      float* __restrict__ cb_vec, float* __restrict__ we2,
                      float* __restrict__ scal)
{
  __shared__ float red1[256], red2[256];
  int n = blockIdx.x, t = threadIdx.x;
  float sp = 0.f, cp = 0.f;
  if (n < NCOL) {
    for (int h = t; h < HD; h += 256) {
      float w = (n < DD) ? sp_w[(size_t)h*DD + n] : W_qkv[(size_t)h*384 + 256 + (n-DD)];
      float g = ln_g[h], b = ln_b[h];
      Bp[(size_t)n*HD + h] = (_Float16)(g*w);
      sp += g*w; cp += b*w;
    }
  } else {
    for (int h = t; h < HD; h += 256) {
      float w = W_eta_w[h];
      float g = ln_g[h], b = ln_b[h];
      we2[h] = g*w;
      sp += g*w; cp += b*w;
    }
  }
  red1[t] = sp; red2[t] = cp;
  __syncthreads();
  for (int o = 128; o > 0; o >>= 1) {
    if (t < o) { red1[t] += red1[t+o]; red2[t] += red2[t+o]; }
    __syncthreads();
  }
  if (t == 0) {
    if (n < NCOL) {
      s_vec[n]  = red1[0];
      cb_vec[n] = red2[0] + ((n < DD) ? sp_b[n] : 0.f);
    } else {
      scal[0] = red1[0];
      scal[1] = red2[0] + W_eta_b[0];
      scal[2] = 0.f; scal[3] = 0.f;
    }
  }
}

// ---------------------------------------------------------------------------
// K01 R15: FUSED n-halves. One 512-thread block per segment (grid 256 =
// 1 block/CU), BM=64 BN=256 BK=64, 8 waves each 64x32 (wave col = w*32).
// Each H tile is now read ONCE (was twice via the ntile split) -> per-CU
// A-traffic halves; per-CU compute unchanged (128 MFMA/iter).
// Schedule: R8/R9-proven syncthreads-only dbuf; A register-staged (R9's
// 8-float strips, 512 threads), B via glds (R12's XOR'd source chunks,
// bn extended to 256 rows; (n&7) swizzle law unchanged since w*32%8==0).
// LDS: sA 2x8K + sB 2x32K = 80K pool; sHm [64][260] aliases pool after
// the stats barrier; segment ops + Q_r writes all in this block.
// ---------------------------------------------------------------------------
#define STAGE_A(sAdst)                                                        \
  {                                                                           \
    float v[8]  = {pa0.x,pa0.y,pa0.z,pa0.w, pa1.x,pa1.y,pa1.z,pa1.w};         \
    float uu[8] = {pw0.x,pw0.y,pw0.z,pw0.w, pw1.x,pw1.y,pw1.z,pw1.w};         \
    _Pragma("unroll")                                                         \
    for (int j = 0; j < 8; ++j) { s1 += v[j]; s2 += v[j]*v[j]; se += v[j]*uu[j]; } \
    half8 h0;                                                                 \
    _Pragma("unroll")                                                         \
    for (int j = 0; j < 8; ++j) { h0[j] = (_Float16)v[j]; }                   \
    *(half8*)&(sAdst)[r_l*64 + (cs ^ (r_l & 7))*8] = h0;                      \
  }

__launch_bounds__(512, 2)
__global__ void k01(const float* __restrict__ H, const _Float16* __restrict__ Bp,
                    const float* __restrict__ s_vec, const float* __restrict__ cb_vec,
                    const float* __restrict__ we2, const float* __restrict__ scal,
                    const float* __restrict__ sum_q, const float* __restrict__ Mmat,
                    const float* __restrict__ temp,
                    float* __restrict__ Q_r, float* __restrict__ Zeta,
                    float* __restrict__ A_seg, float* __restrict__ eta_seg)
{
  __shared__ __align__(16) char pool[81920];   // sA dbuf 16K + sB dbuf 64K | sHm 64x260 f32
  __shared__ float smu[64], srs[64], seta[64];
  __shared__ float sq_s[128], w64_s[64], Zs[128], red_s[4];
  __shared__ float eta_sh_s;
  _Float16* sA0 = (_Float16*)pool;             // [64 rows][8 chunks of 8]
  _Float16* sA1 = (_Float16*)(pool + 8192);
  _Float16* sB0 = (_Float16*)(pool + 16384);   // [256 rows][8 chunks]
  _Float16* sB1 = (_Float16*)(pool + 49152);
  float*    sHm = (float*)pool;                // epilogue alias [64][260]

  int tid = threadIdx.x;
  int seg = blockIdx.x;
  int b   = seg >> 6;
  int m0  = seg * 64;
  int w = tid >> 6, lane = tid & 63, fcol = lane & 15, kq = lane >> 4;

  if (tid < 128) sq_s[tid] = sum_q[tid];
  float scal0 = scal[0], scal1 = scal[1];

  // A loader: thread -> row r_l, 8-float strip at chunk cs (R9-proven)
  int r_l = tid >> 3, cs = tid & 7;
  const float* aptr = H + (size_t)(m0 + r_l)*HD + cs*8;
  const float* wptr = we2 + cs*8;              // same strip of we2 (L2-hot)
  // B loader: 4 glds slots over 256 n-rows, XOR'd source chunk (dest linear)
  int bn[4], bsl[4];
#pragma unroll
  for (int i = 0; i < 4; ++i) {
    int idx = i*512 + tid;
    bn[i]  = idx >> 3;                         // 0..255
    bsl[i] = (idx & 7) ^ (bn[i] & 7);
  }

  f32x4 acc[4][2];
#pragma unroll
  for (int i = 0; i < 4; ++i)
#pragma unroll
    for (int j = 0; j < 2; ++j) acc[i][j] = (f32x4){0.f,0.f,0.f,0.f};
  float s1 = 0.f, s2 = 0.f, se = 0.f;

  // ---- prologue: tile 0 into buf0, prefetch pa/pw(1) ----
  float4 pa0 = *(const float4*)(aptr + 0);
  float4 pa1 = *(const float4*)(aptr + 4);
  float4 pw0 = *(const float4*)(wptr + 0);
  float4 pw1 = *(const float4*)(wptr + 4);
#pragma unroll
  for (int i = 0; i < 4; ++i)
    glds16(Bp + (size_t)bn[i]*HD + bsl[i]*8,
           sB0 + (size_t)(i*512 + tid)*8);
  STAGE_A(sA0);
  {
    const float* ap = aptr + 64;
    pa0 = *(const float4*)(ap + 0); pa1 = *(const float4*)(ap + 4);
    const float* wp = wptr + 64;
    pw0 = *(const float4*)(wp + 0); pw1 = *(const float4*)(wp + 4);
  }
  __syncthreads();   // glds(0) drained, sA0 visible

  for (int kt = 0; kt < 32; ++kt) {
    _Float16* sAc = (kt & 1) ? sA1 : sA0;
    _Float16* sBc = (kt & 1) ? sB1 : sB0;
    _Float16* sAn = (kt & 1) ? sA0 : sA1;
    _Float16* sBn = (kt & 1) ? sB0 : sB1;
    if (kt < 31) {
      int k0n = (kt+1)*64;
#pragma unroll
      for (int i = 0; i < 4; ++i)
        glds16(Bp + (size_t)bn[i]*HD + k0n + bsl[i]*8,
               sBn + (size_t)(i*512 + tid)*8);
      STAGE_A(sAn);                 // consumes pa/pw(kt+1)
      if (kt < 30) {                // prefetch pa/pw(kt+2)
        const float* ap = aptr + (kt+2)*64;
        pa0 = *(const float4*)(ap + 0); pa1 = *(const float4*)(ap + 4);
        const float* wp = wptr + (kt+2)*64;
        pw0 = *(const float4*)(wp + 0); pw1 = *(const float4*)(wp + 4);
      }
    }
    // compute on current buffers: wave w owns cols w*32..w*32+31
    __builtin_amdgcn_s_setprio(1);
#pragma unroll
    for (int ks = 0; ks < 2; ++ks) {
      half8 af[4], bf[2];
#pragma unroll
      for (int rt = 0; rt < 4; ++rt) {
        int r = rt*16 + fcol;
        int ch = (ks*4 + kq) ^ (r & 7);
        af[rt] = *(half8*)&sAc[r*64 + ch*8];
      }
#pragma unroll
      for (int ct = 0; ct < 2; ++ct) {
        int n = w*32 + ct*16 + fcol;     // 0..255; n&7 law unchanged
        int ch = (ks*4 + kq) ^ (n & 7);
        bf[ct] = *(half8*)&sBc[n*64 + ch*8];
      }
#pragma unroll
      for (int rt = 0; rt < 4; ++rt)
#pragma unroll
        for (int ct = 0; ct < 2; ++ct)
          acc[rt][ct] = __builtin_amdgcn_mfma_f32_16x16x32_f16(af[rt], bf[ct], acc[rt][ct], 0,0,0);
    }
    __builtin_amdgcn_s_setprio(0);
    if (kt < 31) __syncthreads();   // drains glds(kt+1), publishes sA(kt+1)
  }

  // row stats: reduce across the 8 strip-threads of each row (same wave)
  s1 += __shfl_xor(s1, 1); s1 += __shfl_xor(s1, 2); s1 += __shfl_xor(s1, 4);
  s2 += __shfl_xor(s2, 1); s2 += __shfl_xor(s2, 2); s2 += __shfl_xor(s2, 4);
  se += __shfl_xor(se, 1); se += __shfl_xor(se, 2); se += __shfl_xor(se, 4);
  if ((tid & 7) == 0) {
    int row = tid >> 3;
    float mu   = s1 * (1.f/HD);
    float var  = s2 * (1.f/HD) - mu*mu;
    float rstd = rsqrtf(var + 1e-5f);
    smu[row] = mu; srs[row] = rstd;
    seta[row] = rstd*(se - mu*scal0) + scal1;
  }
  __syncthreads();   // stats visible; ALL waves' MFMA reads done -> pool reusable

  // epilogue: LN affine -> sHm [64][260], all 256 cols
#pragma unroll
  for (int ct = 0; ct < 2; ++ct) {
    int nl = w*32 + ct*16 + fcol;    // 0..255
    float sn = s_vec[nl], cbn = cb_vec[nl];
#pragma unroll
    for (int rt = 0; rt < 4; ++rt)
#pragma unroll
      for (int r = 0; r < 4; ++r) {
        int m = rt*16 + kq*4 + r;
        sHm[m*260 + nl] = srs[m]*(acc[rt][ct][r] - smu[m]*sn) + cbn;
      }
  }
  __syncthreads();   // sHm ready

  // coalesced Q_r writes (cols 128..255 of sHm)
#pragma unroll
  for (int j = 0; j < 4; ++j) {
    int idx = j*512 + tid;           // 0..2047
    int row = idx >> 5, c4 = (idx & 31)*4;
    *(float4*)&Q_r[(size_t)(m0 + row)*DD + c4] = *(float4*)&sHm[row*260 + 128 + c4];
  }

  // segment ops on H_mem (cols 0..127): summary softmax (wave 0) / eta (wave 1)
  if (w == 0) {
    float sc = 0.f;
    const float* hrow = &sHm[lane*260];
#pragma unroll
    for (int d4 = 0; d4 < 32; ++d4) {
      float4 hv = *(const float4*)&hrow[d4*4];
      float4 qv = *(const float4*)&sq_s[d4*4];
      sc += hv.x*qv.x + hv.y*qv.y + hv.z*qv.z + hv.w*qv.w;
    }
    sc *= SCALE_D;
    float mx = sc;
    for (int o = 32; o > 0; o >>= 1) mx = fmaxf(mx, __shfl_xor(mx, o));
    float e = __expf(sc - mx);
    float sm = e;
    for (int o = 32; o > 0; o >>= 1) sm += __shfl_xor(sm, o);
    w64_s[lane] = e / sm;
  } else if (w == 1) {
    float ev = seta[lane];
    for (int o = 32; o > 0; o >>= 1) ev = fmaxf(ev, __shfl_xor(ev, o));
    if (lane == 0) { float es = sigmf(ev); eta_sh_s = es; eta_seg[seg] = es; }
  }
  __syncthreads();   // w64_s, eta_sh_s ready

  // Z[d] + Zeta
  if (tid < 128) {
    float z = 0.f;
    for (int l = 0; l < 64; ++l) z += w64_s[l]*sHm[l*260 + tid];
    Zs[tid] = z;
    Zeta[(size_t)seg*DD + tid] = z * eta_sh_s;
  }
  __syncthreads();   // Zs ready

  // write-attn scores over K=128 + softmax (flat barriers, R5-proven form)
  float sc2 = 0.f;
  if (tid < 128) {
    const float4* mrow = (const float4*)(Mmat + ((size_t)b*DD + tid)*DD);
#pragma unroll
    for (int d4 = 0; d4 < 32; ++d4) {
      float4 mv = mrow[d4];
      sc2 += mv.x*Zs[d4*4] + mv.y*Zs[d4*4+1] + mv.z*Zs[d4*4+2] + mv.w*Zs[d4*4+3];
    }
    sc2 *= SCALE_D * __expf(temp[0]);
    float mx = sc2;
    for (int o = 32; o > 0; o >>= 1) mx = fmaxf(mx, __shfl_xor(mx, o));
    if (lane == 0) red_s[w] = mx;
  }
  __syncthreads();
  float ev2 = 0.f;
  if (tid < 128) {
    float mx = fmaxf(red_s[0], red_s[1]);
    ev2 = __expf(sc2 - mx);
    float sm = ev2;
    for (int o = 32; o > 0; o >>= 1) sm += __shfl_xor(sm, o);
    if (lane == 0) red_s[2 + w] = sm;
  }
  __syncthreads();
  if (tid < 128) {
    float smt = red_s[2] + red_s[3];
    A_seg[(size_t)seg*DD + tid] = ev2 / smt;
  }
}

// ---------------------------------------------------------------------------
// K2b: DeltaM (k-chunk of 32 per block), M_new, row rnorms, norm_sq atomic.
// ---------------------------------------------------------------------------
__global__ void k2b(const float* __restrict__ A_seg, const float* __restrict__ Zeta,
                    const float* __restrict__ eta_seg, const float* __restrict__ Mmat,
                    const float* __restrict__ eta_ch,
                    float* __restrict__ M_new, float* __restrict__ rns_arr,
                    float* __restrict__ scal)
{
  __shared__ float As[64][33];
  __shared__ __align__(16) float Zsl[64*128];
  __shared__ float rowp[32][8];
  __shared__ float eta_av;
  __shared__ float redb[4];
  int tid = threadIdx.x;
  int b = blockIdx.x >> 2, kq = blockIdx.x & 3;
  for (int i = tid; i < 64*32; i += 256) {
    int s = i >> 5, j = i & 31;
    As[s][j] = A_seg[((size_t)b*SSEG + s)*DD + kq*32 + j];
  }
  const float4* z4 = (const float4*)(Zeta + (size_t)b*SSEG*DD);
  float4* zs4 = (float4*)Zsl;
  for (int i = tid; i < 64*32; i += 256) zs4[i] = z4[i];
  if (tid < 64) {
    float ev = eta_seg[(size_t)b*SSEG + tid];
    for (int o=32;o>0;o>>=1) ev += __shfl_xor(ev, o);
    if (tid == 0) eta_av = ev * (1.f/SSEG);
  }
  __syncthreads();
  int kl = tid & 31, dg = tid >> 5;
  int k = kq*32 + kl, d0 = dg*16;
  float dm[16];
#pragma unroll
  for (int j=0;j<16;j++) dm[j]=0.f;
  for (int s = 0; s < 64; ++s) {
    float a = As[s][kl];
    const float* zr = &Zsl[s*128 + d0];
#pragma unroll
    for (int j=0;j<16;j++) dm[j] += a * zr[j];
  }
  float nsq = 0.f;
#pragma unroll
  for (int j=0;j<16;j++) nsq += dm[j]*dm[j];
  float eav = eta_av;
  float mn[16];
  float ss = 0.f;
#pragma unroll
  for (int j=0;j<16;j++) {
    int d = d0 + j;
    float gate = eav * sigmf(eta_ch[d]);
    float v = (1.f - gate)*Mmat[((size_t)b*DD + k)*DD + d] + dm[j]*(1.f/SSEG);
    mn[j] = v; ss += v*v;
  }
#pragma unroll
  for (int j=0;j<16;j+=4) {
    float4 v4; v4.x=mn[j]; v4.y=mn[j+1]; v4.z=mn[j+2]; v4.w=mn[j+3];
    *(float4*)&M_new[((size_t)b*DD + k)*DD + d0 + j] = v4;
  }
  rowp[kl][dg] = ss;
  for (int o=1;o<64;o<<=1) nsq += __shfl_xor(nsq, o);
  if ((tid&63)==0) redb[tid>>6] = nsq;
  __syncthreads();
  if (tid == 0) atomicAdd(&scal[2], redb[0]+redb[1]+redb[2]+redb[3]);
  if (tid < 32) {
    float t2 = 0.f;
#pragma unroll
    for (int g=0; g<8; ++g) t2 += rowp[tid][g];
    float nrm = sqrtf(t2);
    rns_arr[(size_t)b*DD + kq*32 + tid] = 1.f / fmaxf(nrm, 1e-12f);
  }
}

// ---------------------------------------------------------------------------
// K2d: diversity loss partials.
// ---------------------------------------------------------------------------
__global__ void k2d(const float* __restrict__ M_new, const float* __restrict__ rns_arr,
                    float* __restrict__ scal)
{
  __shared__ float kr[4][128];
  __shared__ float redb[4];
  int tid = threadIdx.x;
  int b = blockIdx.x >> 5, kq = blockIdx.x & 31;
  for (int i = tid; i < 4*128; i += 256) {
    int ki = i >> 7, d = i & 127;
    kr[ki][d] = M_new[((size_t)b*DD + kq*4 + ki)*DD + d];
  }
  __syncthreads();
  int j = tid & 127, kh = tid >> 7;
  const float* mj = &M_new[((size_t)b*DD + j)*DD];
  float rj = rns_arr[(size_t)b*DD + j];
  float dv = 0.f;
#pragma unroll
  for (int ki2 = 0; ki2 < 2; ++ki2) {
    int kil = kh*2 + ki2;
    int kk = kq*4 + kil;
    float dot = 0.f;
    for (int d = 0; d < 128; d += 4) {
      float4 a = *(const float4*)(mj + d);
      dot += a.x*kr[kil][d] + a.y*kr[kil][d+1] + a.z*kr[kil][d+2] + a.w*kr[kil][d+3];
    }
    if (kk != j) {
      float sv = dot * rj * rns_arr[(size_t)b*DD + kk];
      dv += sv*sv;
    }
  }
  for (int o=1;o<64;o<<=1) dv += __shfl_xor(dv, o);
  if ((tid&63)==0) redb[tid>>6] = dv;
  __syncthreads();
  if (tid==0) atomicAdd(&scal[3], redb[0]+redb[1]+redb[2]+redb[3]);
}

// ---------------------------------------------------------------------------
// K3: read attention via MFMA fp16 (fp32 softmax/accum). R12-proven:
// 512 blocks x 128 threads (32-token tiles), LDS 77KB -> 2 blocks/CU.
// ---------------------------------------------------------------------------
__launch_bounds__(128, 1)
__global__ void k3(const float* __restrict__ Q_r, const float* __restrict__ M_new,
                   const float* __restrict__ scal, float* __restrict__ out)
{
  __shared__ __align__(16) _Float16 Mq[128*132];  // [key][d]   (QK B-frags)
  __shared__ __align__(16) _Float16 Mt[128*136];  // [d][key]   (PV B-frags)
  __shared__ __align__(16) _Float16 Ps[32*132];   // [token][key] (PV A-frags)
  int tid = threadIdx.x;
  int b = blockIdx.x >> 7, tile = blockIdx.x & 127;
  int t0 = tile*32;
  if (blockIdx.x == 0 && tid == 0) {
    float loss = 0.01f*(scal[2]*(1.f/SSEG)) + 0.1f*(scal[3]*(1.f/(BB*DD*DD)));
    out[(size_t)MT*DD] = loss;
  }
  const float4* m4 = (const float4*)(M_new + (size_t)b*DD*DD);
#pragma unroll
  for (int it = 0; it < 8; ++it) {
    int sb = it*128 + tid;
    int rb = sb & 31, cb = sb >> 5;
    int r0 = rb*4, c0 = cb*4;
    float a[4][4];
#pragma unroll
    for (int j = 0; j < 4; ++j) {
      float4 v = m4[(size_t)(r0+j)*32 + cb];
      a[j][0]=v.x; a[j][1]=v.y; a[j][2]=v.z; a[j][3]=v.w;
    }
#pragma unroll
    for (int j = 0; j < 4; ++j) {
      half4v h; h.x=(_Float16)a[j][0]; h.y=(_Float16)a[j][1];
                h.z=(_Float16)a[j][2]; h.w=(_Float16)a[j][3];
      *(half4v*)&Mq[(r0+j)*132 + c0] = h;
    }
#pragma unroll
    for (int j2 = 0; j2 < 4; ++j2) {
      half4v h; h.x=(_Float16)a[0][j2]; h.y=(_Float16)a[1][j2];
                h.z=(_Float16)a[2][j2]; h.w=(_Float16)a[3][j2];
      *(half4v*)&Mt[(c0+j2)*136 + r0] = h;
    }
  }
  int w = tid >> 6, lane = tid & 63;
  int fcol = lane & 15, kq = lane >> 4;
  int tokA = t0 + w*16 + fcol;
  size_t qbase = ((size_t)b*TT + tokA)*DD;
  half8 af[4];
#pragma unroll
  for (int ks = 0; ks < 4; ++ks) {
    float4 q0 = *(const float4*)&Q_r[qbase + ks*32 + kq*8];
    float4 q1 = *(const float4*)&Q_r[qbase + ks*32 + kq*8 + 4];
    half8 h;
    h[0]=(_Float16)q0.x; h[1]=(_Float16)q0.y; h[2]=(_Float16)q0.z; h[3]=(_Float16)q0.w;
    h[4]=(_Float16)q1.x; h[5]=(_Float16)q1.y; h[6]=(_Float16)q1.z; h[7]=(_Float16)q1.w;
    af[ks] = h;
  }
  __syncthreads();
  f32x4 sacc[8];
#pragma unroll
  for (int nt = 0; nt < 8; ++nt) sacc[nt] = (f32x4){0.f,0.f,0.f,0.f};
#pragma unroll
  for (int nt = 0; nt < 8; ++nt)
#pragma unroll
    for (int ks = 0; ks < 4; ++ks) {
      half8 bf = *(half8*)&Mq[(nt*16 + fcol)*132 + ks*32 + kq*8];
      sacc[nt] = __builtin_amdgcn_mfma_f32_16x16x32_f16(af[ks], bf, sacc[nt], 0,0,0);
    }
#pragma unroll
  for (int nt = 0; nt < 8; ++nt)
#pragma unroll
    for (int r = 0; r < 4; ++r) sacc[nt][r] *= 2.f;
  float mx[4], sm[4];
#pragma unroll
  for (int r = 0; r < 4; ++r) {
    float m = sacc[0][r];
#pragma unroll
    for (int nt = 1; nt < 8; ++nt) m = fmaxf(m, sacc[nt][r]);
#pragma unroll
    for (int o = 1; o < 16; o <<= 1) m = fmaxf(m, __shfl_xor(m, o));
    mx[r] = m;
  }
#pragma unroll
  for (int r = 0; r < 4; ++r) sm[r] = 0.f;
#pragma unroll
  for (int nt = 0; nt < 8; ++nt)
#pragma unroll
    for (int r = 0; r < 4; ++r) {
      float e = __expf(sacc[nt][r] - mx[r]);
      sacc[nt][r] = e; sm[r] += e;
    }
#pragma unroll
  for (int r = 0; r < 4; ++r) {
    float s = sm[r];
#pragma unroll
    for (int o = 1; o < 16; o <<= 1) s += __shfl_xor(s, o);
    sm[r] = 1.f / s;
  }
#pragma unroll
  for (int nt = 0; nt < 8; ++nt)
#pragma unroll
    for (int r = 0; r < 4; ++r) {
      int tk = w*16 + kq*4 + r;
      Ps[tk*132 + nt*16 + fcol] = (_Float16)(sacc[nt][r]*sm[r]);
    }
  __syncthreads();
  half8 pf[4];
#pragma unroll
  for (int ks = 0; ks < 4; ++ks)
    pf[ks] = *(half8*)&Ps[(w*16 + fcol)*132 + ks*32 + kq*8];
  f32x4 cacc[8];
#pragma unroll
  for (int nt = 0; nt < 8; ++nt) cacc[nt] = (f32x4){0.f,0.f,0.f,0.f};
#pragma unroll
  for (int nt = 0; nt < 8; ++nt)
#pragma unroll
    for (int ks = 0; ks < 4; ++ks) {
      half8 bf = *(half8*)&Mt[(nt*16 + fcol)*136 + ks*32 + kq*8];
      cacc[nt] = __builtin_amdgcn_mfma_f32_16x16x32_f16(pf[ks], bf, cacc[nt], 0,0,0);
    }
#pragma unroll
  for (int nt = 0; nt < 8; ++nt)
#pragma unroll
    for (int r = 0; r < 4; ++r) {
      int tk = t0 + w*16 + kq*4 + r;
      out[((size_t)b*TT + tk)*DD + nt*16 + fcol] = cacc[nt][r];
    }
}

// ---------------------------------------------------------------------------
extern "C" void kernel_launch(void* const* d_in, const int* in_sizes, int n_in,
                              void* d_out, int out_size, void* d_ws, size_t ws_size,
                              hipStream_t stream)
{
  (void)in_sizes; (void)n_in; (void)out_size; (void)ws_size;
  const float* H       = (const float*)d_in[0];
  const float* Mmat    = (const float*)d_in[1];
  const float* ln_g    = (const float*)d_in[2];
  const float* ln_b    = (const float*)d_in[3];
  const float* W_eta_w = (const float*)d_in[4];
  const float* W_eta_b = (const float*)d_in[5];
  const float* sum_q   = (const float*)d_in[6];
  const float* sp_w    = (const float*)d_in[7];
  const float* sp_b    = (const float*)d_in[8];
  const float* eta_ch  = (const float*)d_in[9];
  const float* temp    = (const float*)d_in[10];
  const float* W_qkv   = (const float*)d_in[11];
  float* out           = (float*)d_out;

  char* wsb = (char*)d_ws;
  size_t off = 0;
  auto alloc = [&](size_t bytes) -> void* {
    void* p = wsb + off;
    off = (off + bytes + 255) & ~(size_t)255;
    return p;
  };
  _Float16* Bp   = (_Float16*)alloc((size_t)NCOL*HD*2);
  float* s_vec   = (float*)alloc(NCOL*4);
  float* cb_vec  = (float*)alloc(NCOL*4);
  float* we2     = (float*)alloc(HD*4);
  float* scal    = (float*)alloc(4*4);
  float* Q_r     = (float*)alloc((size_t)MT*DD*4);
  float* Zeta    = (float*)alloc((size_t)BB*SSEG*DD*4);
  float* A_seg   = (float*)alloc((size_t)BB*SSEG*DD*4);
  float* eta_seg = (float*)alloc((size_t)BB*SSEG*4);
  float* M_new   = (float*)alloc((size_t)BB*DD*DD*4);
  float* rns_arr = (float*)alloc((size_t)BB*DD*4);

  hipLaunchKernelGGL(k_pre, dim3(NCOL+1), dim3(256), 0, stream,
                     ln_g, ln_b, sp_w, sp_b, W_qkv, W_eta_w, W_eta_b,
                     Bp, s_vec, cb_vec, we2, scal);
  hipLaunchKernelGGL(k01, dim3(MT/64), dim3(512), 0, stream,
                     H, Bp, s_vec, cb_vec, we2, scal, sum_q, Mmat, temp,
                     Q_r, Zeta, A_seg, eta_seg);
  hipLaunchKernelGGL(k2b, dim3(16), dim3(256), 0, stream,
                     A_seg, Zeta, eta_seg, Mmat, eta_ch, M_new, rns_arr, scal);
  hipLaunchKernelGGL(k2d, dim3(128), dim3(256), 0, stream,
                     M_new, rns_arr, scal);
  hipLaunchKernelGGL(k3, dim3(512), dim3(128), 0, stream,
                     Q_r, M_new, scal, out);
}

// Round 11
// 272.273 us; speedup vs baseline: 1.0494x; 1.0079x over previous
//
#include <hip/hip_runtime.h>
#include <hip/hip_bf16.h>
#include <math.h>

#define HD   2048
#define DD   128
#define TT   4096
#define BB   4
#define MT   (BB*TT)     // 16384 tokens
#define LSEG 64
#define SSEG 64
#define NCOL 256
#define SCALE_D 0.088388347648318447f  // 1/sqrt(128)

typedef _Float16 half8 __attribute__((ext_vector_type(8)));
typedef _Float16 half4v __attribute__((ext_vector_type(4)));
typedef float    f32x4 __attribute__((ext_vector_type(4)));

__device__ __forceinline__ float sigmf(float x){ return 1.f/(1.f+__expf(-x)); }

__device__ __forceinline__ void glds16(const void* g, void* l) {
  __builtin_amdgcn_global_load_lds(
      (const __attribute__((address_space(1))) unsigned int*)g,
      (__attribute__((address_space(3))) unsigned int*)l, 16, 0, 0);
}

// ---------------------------------------------------------------------------
// K_pre: pack B' = g (.) [sp_w | W_q] as fp16, n-major [256][2048], LINEAR
// storage (R5-proven). Per-col sums s_n, cb_n; we2 = g*w_eta;
// scal = {s_eta, cb_eta, 0, 0}
// ---------------------------------------------------------------------------
__global__ void k_pre(const float* __restrict__ ln_g, const float* __restrict__ ln_b,
                      const float* __restrict__ sp_w, const float* __restrict__ sp_b,
                      const float* __restrict__ W_qkv, const float* __restrict__ W_eta_w,
                      const float* __restrict__ W_eta_b,
                      _Float16* __restrict__ Bp, float* __restrict__ s_vec,
                      float* __restrict__ cb_vec, float* __restrict__ we2,
                      float* __restrict__ scal)
{
  __shared__ float red1[256], red2[256];
  int n = blockIdx.x, t = threadIdx.x;
  float sp = 0.f, cp = 0.f;
  if (n < NCOL) {
    for (int h = t; h < HD; h += 256) {
      float w = (n < DD) ? sp_w[(size_t)h*DD + n] : W_qkv[(size_t)h*384 + 256 + (n-DD)];
      float g = ln_g[h], b = ln_b[h];
      Bp[(size_t)n*HD + h] = (_Float16)(g*w);
      sp += g*w; cp += b*w;
    }
  } else {
    for (int h = t; h < HD; h += 256) {
      float w = W_eta_w[h];
      float g = ln_g[h], b = ln_b[h];
      we2[h] = g*w;
      sp += g*w; cp += b*w;
    }
  }
  red1[t] = sp; red2[t] = cp;
  __syncthreads();
  for (int o = 128; o > 0; o >>= 1) {
    if (t < o) { red1[t] += red1[t+o]; red2[t] += red2[t+o]; }
    __syncthreads();
  }
  if (t == 0) {
    if (n < NCOL) {
      s_vec[n]  = red1[0];
      cb_vec[n] = red2[0] + ((n < DD) ? sp_b[n] : 0.f);
    } else {
      scal[0] = red1[0];
      scal[1] = red2[0] + W_eta_b[0];
      scal[2] = 0.f; scal[3] = 0.f;
    }
  }
}

// ---------------------------------------------------------------------------
// K01 R15 (VERBATIM, passed @274.4us): FUSED n-halves. One 512-thread block
// per segment (grid 256 = 1 block/CU), BM=64 BN=256 BK=64, 8 waves.
// H tile read ONCE; syncthreads-only dbuf; A reg-staged; B via glds.
// ---------------------------------------------------------------------------
#define STAGE_A(sAdst)                                                        \
  {                                                                           \
    float v[8]  = {pa0.x,pa0.y,pa0.z,pa0.w, pa1.x,pa1.y,pa1.z,pa1.w};         \
    float uu[8] = {pw0.x,pw0.y,pw0.z,pw0.w, pw1.x,pw1.y,pw1.z,pw1.w};         \
    _Pragma("unroll")                                                         \
    for (int j = 0; j < 8; ++j) { s1 += v[j]; s2 += v[j]*v[j]; se += v[j]*uu[j]; } \
    half8 h0;                                                                 \
    _Pragma("unroll")                                                         \
    for (int j = 0; j < 8; ++j) { h0[j] = (_Float16)v[j]; }                   \
    *(half8*)&(sAdst)[r_l*64 + (cs ^ (r_l & 7))*8] = h0;                      \
  }

__launch_bounds__(512, 2)
__global__ void k01(const float* __restrict__ H, const _Float16* __restrict__ Bp,
                    const float* __restrict__ s_vec, const float* __restrict__ cb_vec,
                    const float* __restrict__ we2, const float* __restrict__ scal,
                    const float* __restrict__ sum_q, const float* __restrict__ Mmat,
                    const float* __restrict__ temp,
                    float* __restrict__ Q_r, float* __restrict__ Zeta,
                    float* __restrict__ A_seg, float* __restrict__ eta_seg)
{
  __shared__ __align__(16) char pool[81920];   // sA dbuf 16K + sB dbuf 64K | sHm 64x260 f32
  __shared__ float smu[64], srs[64], seta[64];
  __shared__ float sq_s[128], w64_s[64], Zs[128], red_s[4];
  __shared__ float eta_sh_s;
  _Float16* sA0 = (_Float16*)pool;             // [64 rows][8 chunks of 8]
  _Float16* sA1 = (_Float16*)(pool + 8192);
  _Float16* sB0 = (_Float16*)(pool + 16384);   // [256 rows][8 chunks]
  _Float16* sB1 = (_Float16*)(pool + 49152);
  float*    sHm = (float*)pool;                // epilogue alias [64][260]

  int tid = threadIdx.x;
  int seg = blockIdx.x;
  int b   = seg >> 6;
  int m0  = seg * 64;
  int w = tid >> 6, lane = tid & 63, fcol = lane & 15, kq = lane >> 4;

  if (tid < 128) sq_s[tid] = sum_q[tid];
  float scal0 = scal[0], scal1 = scal[1];

  // A loader: thread -> row r_l, 8-float strip at chunk cs (R9-proven)
  int r_l = tid >> 3, cs = tid & 7;
  const float* aptr = H + (size_t)(m0 + r_l)*HD + cs*8;
  const float* wptr = we2 + cs*8;              // same strip of we2 (L2-hot)
  // B loader: 4 glds slots over 256 n-rows, XOR'd source chunk (dest linear)
  int bn[4], bsl[4];
#pragma unroll
  for (int i = 0; i < 4; ++i) {
    int idx = i*512 + tid;
    bn[i]  = idx >> 3;                         // 0..255
    bsl[i] = (idx & 7) ^ (bn[i] & 7);
  }

  f32x4 acc[4][2];
#pragma unroll
  for (int i = 0; i < 4; ++i)
#pragma unroll
    for (int j = 0; j < 2; ++j) acc[i][j] = (f32x4){0.f,0.f,0.f,0.f};
  float s1 = 0.f, s2 = 0.f, se = 0.f;

  // ---- prologue: tile 0 into buf0, prefetch pa/pw(1) ----
  float4 pa0 = *(const float4*)(aptr + 0);
  float4 pa1 = *(const float4*)(aptr + 4);
  float4 pw0 = *(const float4*)(wptr + 0);
  float4 pw1 = *(const float4*)(wptr + 4);
#pragma unroll
  for (int i = 0; i < 4; ++i)
    glds16(Bp + (size_t)bn[i]*HD + bsl[i]*8,
           sB0 + (size_t)(i*512 + tid)*8);
  STAGE_A(sA0);
  {
    const float* ap = aptr + 64;
    pa0 = *(const float4*)(ap + 0); pa1 = *(const float4*)(ap + 4);
    const float* wp = wptr + 64;
    pw0 = *(const float4*)(wp + 0); pw1 = *(const float4*)(wp + 4);
  }
  __syncthreads();   // glds(0) drained, sA0 visible

  for (int kt = 0; kt < 32; ++kt) {
    _Float16* sAc = (kt & 1) ? sA1 : sA0;
    _Float16* sBc = (kt & 1) ? sB1 : sB0;
    _Float16* sAn = (kt & 1) ? sA0 : sA1;
    _Float16* sBn = (kt & 1) ? sB0 : sB1;
    if (kt < 31) {
      int k0n = (kt+1)*64;
#pragma unroll
      for (int i = 0; i < 4; ++i)
        glds16(Bp + (size_t)bn[i]*HD + k0n + bsl[i]*8,
               sBn + (size_t)(i*512 + tid)*8);
      STAGE_A(sAn);                 // consumes pa/pw(kt+1)
      if (kt < 30) {                // prefetch pa/pw(kt+2)
        const float* ap = aptr + (kt+2)*64;
        pa0 = *(const float4*)(ap + 0); pa1 = *(const float4*)(ap + 4);
        const float* wp = wptr + (kt+2)*64;
        pw0 = *(const float4*)(wp + 0); pw1 = *(const float4*)(wp + 4);
      }
    }
    // compute on current buffers: wave w owns cols w*32..w*32+31
    __builtin_amdgcn_s_setprio(1);
#pragma unroll
    for (int ks = 0; ks < 2; ++ks) {
      half8 af[4], bf[2];
#pragma unroll
      for (int rt = 0; rt < 4; ++rt) {
        int r = rt*16 + fcol;
        int ch = (ks*4 + kq) ^ (r & 7);
        af[rt] = *(half8*)&sAc[r*64 + ch*8];
      }
#pragma unroll
      for (int ct = 0; ct < 2; ++ct) {
        int n = w*32 + ct*16 + fcol;     // 0..255; n&7 law unchanged
        int ch = (ks*4 + kq) ^ (n & 7);
        bf[ct] = *(half8*)&sBc[n*64 + ch*8];
      }
#pragma unroll
      for (int rt = 0; rt < 4; ++rt)
#pragma unroll
        for (int ct = 0; ct < 2; ++ct)
          acc[rt][ct] = __builtin_amdgcn_mfma_f32_16x16x32_f16(af[rt], bf[ct], acc[rt][ct], 0,0,0);
    }
    __builtin_amdgcn_s_setprio(0);
    if (kt < 31) __syncthreads();   // drains glds(kt+1), publishes sA(kt+1)
  }

  // row stats: reduce across the 8 strip-threads of each row (same wave)
  s1 += __shfl_xor(s1, 1); s1 += __shfl_xor(s1, 2); s1 += __shfl_xor(s1, 4);
  s2 += __shfl_xor(s2, 1); s2 += __shfl_xor(s2, 2); s2 += __shfl_xor(s2, 4);
  se += __shfl_xor(se, 1); se += __shfl_xor(se, 2); se += __shfl_xor(se, 4);
  if ((tid & 7) == 0) {
    int row = tid >> 3;
    float mu   = s1 * (1.f/HD);
    float var  = s2 * (1.f/HD) - mu*mu;
    float rstd = rsqrtf(var + 1e-5f);
    smu[row] = mu; srs[row] = rstd;
    seta[row] = rstd*(se - mu*scal0) + scal1;
  }
  __syncthreads();   // stats visible; ALL waves' MFMA reads done -> pool reusable

  // epilogue: LN affine -> sHm [64][260], all 256 cols
#pragma unroll
  for (int ct = 0; ct < 2; ++ct) {
    int nl = w*32 + ct*16 + fcol;    // 0..255
    float sn = s_vec[nl], cbn = cb_vec[nl];
#pragma unroll
    for (int rt = 0; rt < 4; ++rt)
#pragma unroll
      for (int r = 0; r < 4; ++r) {
        int m = rt*16 + kq*4 + r;
        sHm[m*260 + nl] = srs[m]*(acc[rt][ct][r] - smu[m]*sn) + cbn;
      }
  }
  __syncthreads();   // sHm ready

  // coalesced Q_r writes (cols 128..255 of sHm)
#pragma unroll
  for (int j = 0; j < 4; ++j) {
    int idx = j*512 + tid;           // 0..2047
    int row = idx >> 5, c4 = (idx & 31)*4;
    *(float4*)&Q_r[(size_t)(m0 + row)*DD + c4] = *(float4*)&sHm[row*260 + 128 + c4];
  }

  // segment ops on H_mem (cols 0..127): summary softmax (wave 0) / eta (wave 1)
  if (w == 0) {
    float sc = 0.f;
    const float* hrow = &sHm[lane*260];
#pragma unroll
    for (int d4 = 0; d4 < 32; ++d4) {
      float4 hv = *(const float4*)&hrow[d4*4];
      float4 qv = *(const float4*)&sq_s[d4*4];
      sc += hv.x*qv.x + hv.y*qv.y + hv.z*qv.z + hv.w*qv.w;
    }
    sc *= SCALE_D;
    float mx = sc;
    for (int o = 32; o > 0; o >>= 1) mx = fmaxf(mx, __shfl_xor(mx, o));
    float e = __expf(sc - mx);
    float sm = e;
    for (int o = 32; o > 0; o >>= 1) sm += __shfl_xor(sm, o);
    w64_s[lane] = e / sm;
  } else if (w == 1) {
    float ev = seta[lane];
    for (int o = 32; o > 0; o >>= 1) ev = fmaxf(ev, __shfl_xor(ev, o));
    if (lane == 0) { float es = sigmf(ev); eta_sh_s = es; eta_seg[seg] = es; }
  }
  __syncthreads();   // w64_s, eta_sh_s ready

  // Z[d] + Zeta
  if (tid < 128) {
    float z = 0.f;
    for (int l = 0; l < 64; ++l) z += w64_s[l]*sHm[l*260 + tid];
    Zs[tid] = z;
    Zeta[(size_t)seg*DD + tid] = z * eta_sh_s;
  }
  __syncthreads();   // Zs ready

  // write-attn scores over K=128 + softmax (flat barriers, R5-proven form)
  float sc2 = 0.f;
  if (tid < 128) {
    const float4* mrow = (const float4*)(Mmat + ((size_t)b*DD + tid)*DD);
#pragma unroll
    for (int d4 = 0; d4 < 32; ++d4) {
      float4 mv = mrow[d4];
      sc2 += mv.x*Zs[d4*4] + mv.y*Zs[d4*4+1] + mv.z*Zs[d4*4+2] + mv.w*Zs[d4*4+3];
    }
    sc2 *= SCALE_D * __expf(temp[0]);
    float mx = sc2;
    for (int o = 32; o > 0; o >>= 1) mx = fmaxf(mx, __shfl_xor(mx, o));
    if (lane == 0) red_s[w] = mx;
  }
  __syncthreads();
  float ev2 = 0.f;
  if (tid < 128) {
    float mx = fmaxf(red_s[0], red_s[1]);
    ev2 = __expf(sc2 - mx);
    float sm = ev2;
    for (int o = 32; o > 0; o >>= 1) sm += __shfl_xor(sm, o);
    if (lane == 0) red_s[2 + w] = sm;
  }
  __syncthreads();
  if (tid < 128) {
    float smt = red_s[2] + red_s[3];
    A_seg[(size_t)seg*DD + tid] = ev2 / smt;
  }
}

// ---------------------------------------------------------------------------
// K2b R16: 512 threads (was 256) — per-thread serial work halved.
// 16 blocks, each (b, kq): kl = tid&31 (k-lane), dg = tid>>5 (0..15),
// each thread owns 8 d's. rowp [32][16]; redb[8] (8 waves).
// ---------------------------------------------------------------------------
__global__ void k2b(const float* __restrict__ A_seg, const float* __restrict__ Zeta,
                    const float* __restrict__ eta_seg, const float* __restrict__ Mmat,
                    const float* __restrict__ eta_ch,
                    float* __restrict__ M_new, float* __restrict__ rns_arr,
                    float* __restrict__ scal)
{
  __shared__ float As[64][33];
  __shared__ __align__(16) float Zsl[64*128];
  __shared__ float rowp[32][16];
  __shared__ float eta_av;
  __shared__ float redb[8];
  int tid = threadIdx.x;
  int b = blockIdx.x >> 2, kq = blockIdx.x & 3;
  for (int i = tid; i < 64*32; i += 512) {
    int s = i >> 5, j = i & 31;
    As[s][j] = A_seg[((size_t)b*SSEG + s)*DD + kq*32 + j];
  }
  const float4* z4 = (const float4*)(Zeta + (size_t)b*SSEG*DD);
  float4* zs4 = (float4*)Zsl;
  for (int i = tid; i < 64*32; i += 512) zs4[i] = z4[i];
  if (tid < 64) {
    float ev = eta_seg[(size_t)b*SSEG + tid];
    for (int o=32;o>0;o>>=1) ev += __shfl_xor(ev, o);
    if (tid == 0) eta_av = ev * (1.f/SSEG);
  }
  __syncthreads();
  int kl = tid & 31, dg = tid >> 5;        // dg 0..15
  int k = kq*32 + kl, d0 = dg*8;
  float dm[8];
#pragma unroll
  for (int j=0;j<8;j++) dm[j]=0.f;
  for (int s = 0; s < 64; ++s) {
    float a = As[s][kl];
    const float* zr = &Zsl[s*128 + d0];
#pragma unroll
    for (int j=0;j<8;j++) dm[j] += a * zr[j];
  }
  float nsq = 0.f;
#pragma unroll
  for (int j=0;j<8;j++) nsq += dm[j]*dm[j];
  float eav = eta_av;
  float mn[8];
  float ss = 0.f;
#pragma unroll
  for (int j=0;j<8;j++) {
    int d = d0 + j;
    float gate = eav * sigmf(eta_ch[d]);
    float v = (1.f - gate)*Mmat[((size_t)b*DD + k)*DD + d] + dm[j]*(1.f/SSEG);
    mn[j] = v; ss += v*v;
  }
#pragma unroll
  for (int j=0;j<8;j+=4) {
    float4 v4; v4.x=mn[j]; v4.y=mn[j+1]; v4.z=mn[j+2]; v4.w=mn[j+3];
    *(float4*)&M_new[((size_t)b*DD + k)*DD + d0 + j] = v4;
  }
  rowp[kl][dg] = ss;
  for (int o=1;o<64;o<<=1) nsq += __shfl_xor(nsq, o);
  if ((tid&63)==0) redb[tid>>6] = nsq;
  __syncthreads();
  if (tid == 0) {
    float t = 0.f;
#pragma unroll
    for (int g=0; g<8; ++g) t += redb[g];
    atomicAdd(&scal[2], t);
  }
  if (tid < 32) {
    float t2 = 0.f;
#pragma unroll
    for (int g=0; g<16; ++g) t2 += rowp[tid][g];
    float nrm = sqrtf(t2);
    rns_arr[(size_t)b*DD + kq*32 + tid] = 1.f / fmaxf(nrm, 1e-12f);
  }
}

// ---------------------------------------------------------------------------
// K2d R16: 512 threads (was 256) — one (kk, j) dot per thread (was 2).
// 128 blocks, kh = tid>>7 in 0..3, j = tid&127; redb[8].
// ---------------------------------------------------------------------------
__global__ void k2d(const float* __restrict__ M_new, const float* __restrict__ rns_arr,
                    float* __restrict__ scal)
{
  __shared__ float kr[4][128];
  __shared__ float redb[8];
  int tid = threadIdx.x;
  int b = blockIdx.x >> 5, kq = blockIdx.x & 31;
  {
    int ki = tid >> 7, d = tid & 127;      // 512 threads = exactly 4*128
    kr[ki][d] = M_new[((size_t)b*DD + kq*4 + ki)*DD + d];
  }
  __syncthreads();
  int j = tid & 127, kh = tid >> 7;        // kh 0..3
  const float* mj = &M_new[((size_t)b*DD + j)*DD];
  float rj = rns_arr[(size_t)b*DD + j];
  float dv = 0.f;
  {
    int kk = kq*4 + kh;
    float dot = 0.f;
    for (int d = 0; d < 128; d += 4) {
      float4 a = *(const float4*)(mj + d);
      dot += a.x*kr[kh][d] + a.y*kr[kh][d+1] + a.z*kr[kh][d+2] + a.w*kr[kh][d+3];
    }
    if (kk != j) {
      float sv = dot * rj * rns_arr[(size_t)b*DD + kk];
      dv = sv*sv;
    }
  }
  for (int o=1;o<64;o<<=1) dv += __shfl_xor(dv, o);
  if ((tid&63)==0) redb[tid>>6] = dv;
  __syncthreads();
  if (tid==0) {
    float t = 0.f;
#pragma unroll
    for (int g=0; g<8; ++g) t += redb[g];
    atomicAdd(&scal[3], t);
  }
}

// ---------------------------------------------------------------------------
// K3: read attention via MFMA fp16 (fp32 softmax/accum). R12-proven:
// 512 blocks x 128 threads (32-token tiles), LDS 77KB -> 2 blocks/CU.
// ---------------------------------------------------------------------------
__launch_bounds__(128, 1)
__global__ void k3(const float* __restrict__ Q_r, const float* __restrict__ M_new,
                   const float* __restrict__ scal, float* __restrict__ out)
{
  __shared__ __align__(16) _Float16 Mq[128*132];  // [key][d]   (QK B-frags)
  __shared__ __align__(16) _Float16 Mt[128*136];  // [d][key]   (PV B-frags)
  __shared__ __align__(16) _Float16 Ps[32*132];   // [token][key] (PV A-frags)
  int tid = threadIdx.x;
  int b = blockIdx.x >> 7, tile = blockIdx.x & 127;
  int t0 = tile*32;
  if (blockIdx.x == 0 && tid == 0) {
    float loss = 0.01f*(scal[2]*(1.f/SSEG)) + 0.1f*(scal[3]*(1.f/(BB*DD*DD)));
    out[(size_t)MT*DD] = loss;
  }
  const float4* m4 = (const float4*)(M_new + (size_t)b*DD*DD);
#pragma unroll
  for (int it = 0; it < 8; ++it) {
    int sb = it*128 + tid;
    int rb = sb & 31, cb = sb >> 5;
    int r0 = rb*4, c0 = cb*4;
    float a[4][4];
#pragma unroll
    for (int j = 0; j < 4; ++j) {
      float4 v = m4[(size_t)(r0+j)*32 + cb];
      a[j][0]=v.x; a[j][1]=v.y; a[j][2]=v.z; a[j][3]=v.w;
    }
#pragma unroll
    for (int j = 0; j < 4; ++j) {
      half4v h; h.x=(_Float16)a[j][0]; h.y=(_Float16)a[j][1];
                h.z=(_Float16)a[j][2]; h.w=(_Float16)a[j][3];
      *(half4v*)&Mq[(r0+j)*132 + c0] = h;
    }
#pragma unroll
    for (int j2 = 0; j2 < 4; ++j2) {
      half4v h; h.x=(_Float16)a[0][j2]; h.y=(_Float16)a[1][j2];
                h.z=(_Float16)a[2][j2]; h.w=(_Float16)a[3][j2];
      *(half4v*)&Mt[(c0+j2)*136 + r0] = h;
    }
  }
  int w = tid >> 6, lane = tid & 63;
  int fcol = lane & 15, kq = lane >> 4;
  int tokA = t0 + w*16 + fcol;
  size_t qbase = ((size_t)b*TT + tokA)*DD;
  half8 af[4];
#pragma unroll
  for (int ks = 0; ks < 4; ++ks) {
    float4 q0 = *(const float4*)&Q_r[qbase + ks*32 + kq*8];
    float4 q1 = *(const float4*)&Q_r[qbase + ks*32 + kq*8 + 4];
    half8 h;
    h[0]=(_Float16)q0.x; h[1]=(_Float16)q0.y; h[2]=(_Float16)q0.z; h[3]=(_Float16)q0.w;
    h[4]=(_Float16)q1.x; h[5]=(_Float16)q1.y; h[6]=(_Float16)q1.z; h[7]=(_Float16)q1.w;
    af[ks] = h;
  }
  __syncthreads();
  f32x4 sacc[8];
#pragma unroll
  for (int nt = 0; nt < 8; ++nt) sacc[nt] = (f32x4){0.f,0.f,0.f,0.f};
#pragma unroll
  for (int nt = 0; nt < 8; ++nt)
#pragma unroll
    for (int ks = 0; ks < 4; ++ks) {
      half8 bf = *(half8*)&Mq[(nt*16 + fcol)*132 + ks*32 + kq*8];
      sacc[nt] = __builtin_amdgcn_mfma_f32_16x16x32_f16(af[ks], bf, sacc[nt], 0,0,0);
    }
#pragma unroll
  for (int nt = 0; nt < 8; ++nt)
#pragma unroll
    for (int r = 0; r < 4; ++r) sacc[nt][r] *= 2.f;
  float mx[4], sm[4];
#pragma unroll
  for (int r = 0; r < 4; ++r) {
    float m = sacc[0][r];
#pragma unroll
    for (int nt = 1; nt < 8; ++nt) m = fmaxf(m, sacc[nt][r]);
#pragma unroll
    for (int o = 1; o < 16; o <<= 1) m = fmaxf(m, __shfl_xor(m, o));
    mx[r] = m;
  }
#pragma unroll
  for (int r = 0; r < 4; ++r) sm[r] = 0.f;
#pragma unroll
  for (int nt = 0; nt < 8; ++nt)
#pragma unroll
    for (int r = 0; r < 4; ++r) {
      float e = __expf(sacc[nt][r] - mx[r]);
      sacc[nt][r] = e; sm[r] += e;
    }
#pragma unroll
  for (int r = 0; r < 4; ++r) {
    float s = sm[r];
#pragma unroll
    for (int o = 1; o < 16; o <<= 1) s += __shfl_xor(s, o);
    sm[r] = 1.f / s;
  }
#pragma unroll
  for (int nt = 0; nt < 8; ++nt)
#pragma unroll
    for (int r = 0; r < 4; ++r) {
      int tk = w*16 + kq*4 + r;
      Ps[tk*132 + nt*16 + fcol] = (_Float16)(sacc[nt][r]*sm[r]);
    }
  __syncthreads();
  half8 pf[4];
#pragma unroll
  for (int ks = 0; ks < 4; ++ks)
    pf[ks] = *(half8*)&Ps[(w*16 + fcol)*132 + ks*32 + kq*8];
  f32x4 cacc[8];
#pragma unroll
  for (int nt = 0; nt < 8; ++nt) cacc[nt] = (f32x4){0.f,0.f,0.f,0.f};
#pragma unroll
  for (int nt = 0; nt < 8; ++nt)
#pragma unroll
    for (int ks = 0; ks < 4; ++ks) {
      half8 bf = *(half8*)&Mt[(nt*16 + fcol)*136 + ks*32 + kq*8];
      cacc[nt] = __builtin_amdgcn_mfma_f32_16x16x32_f16(pf[ks], bf, cacc[nt], 0,0,0);
    }
#pragma unroll
  for (int nt = 0; nt < 8; ++nt)
#pragma unroll
    for (int r = 0; r < 4; ++r) {
      int tk = t0 + w*16 + kq*4 + r;
      out[((size_t)b*TT + tk)*DD + nt*16 + fcol] = cacc[nt][r];
    }
}

// ---------------------------------------------------------------------------
extern "C" void kernel_launch(void* const* d_in, const int* in_sizes, int n_in,
                              void* d_out, int out_size, void* d_ws, size_t ws_size,
                              hipStream_t stream)
{
  (void)in_sizes; (void)n_in; (void)out_size; (void)ws_size;
  const float* H       = (const float*)d_in[0];
  const float* Mmat    = (const float*)d_in[1];
  const float* ln_g    = (const float*)d_in[2];
  const float* ln_b    = (const float*)d_in[3];
  const float* W_eta_w = (const float*)d_in[4];
  const float* W_eta_b = (const float*)d_in[5];
  const float* sum_q   = (const float*)d_in[6];
  const float* sp_w    = (const float*)d_in[7];
  const float* sp_b    = (const float*)d_in[8];
  const float* eta_ch  = (const float*)d_in[9];
  const float* temp    = (const float*)d_in[10];
  const float* W_qkv   = (const float*)d_in[11];
  float* out           = (float*)d_out;

  char* wsb = (char*)d_ws;
  size_t off = 0;
  auto alloc = [&](size_t bytes) -> void* {
    void* p = wsb + off;
    off = (off + bytes + 255) & ~(size_t)255;
    return p;
  };
  _Float16* Bp   = (_Float16*)alloc((size_t)NCOL*HD*2);
  float* s_vec   = (float*)alloc(NCOL*4);
  float* cb_vec  = (float*)alloc(NCOL*4);
  float* we2     = (float*)alloc(HD*4);
  float* scal    = (float*)alloc(4*4);
  float* Q_r     = (float*)alloc((size_t)MT*DD*4);
  float* Zeta    = (float*)alloc((size_t)BB*SSEG*DD*4);
  float* A_seg   = (float*)alloc((size_t)BB*SSEG*DD*4);
  float* eta_seg = (float*)alloc((size_t)BB*SSEG*4);
  float* M_new   = (float*)alloc((size_t)BB*DD*DD*4);
  float* rns_arr = (float*)alloc((size_t)BB*DD*4);

  hipLaunchKernelGGL(k_pre, dim3(NCOL+1), dim3(256), 0, stream,
                     ln_g, ln_b, sp_w, sp_b, W_qkv, W_eta_w, W_eta_b,
                     Bp, s_vec, cb_vec, we2, scal);
  hipLaunchKernelGGL(k01, dim3(MT/64), dim3(512), 0, stream,
                     H, Bp, s_vec, cb_vec, we2, scal, sum_q, Mmat, temp,
                     Q_r, Zeta, A_seg, eta_seg);
  hipLaunchKernelGGL(k2b, dim3(16), dim3(512), 0, stream,
                     A_seg, Zeta, eta_seg, Mmat, eta_ch, M_new, rns_arr, scal);
  hipLaunchKernelGGL(k2d, dim3(128), dim3(512), 0, stream,
                     M_new, rns_arr, scal);
  hipLaunchKernelGGL(k3, dim3(512), dim3(128), 0, stream,
                     Q_r, M_new, scal, out);
}